// Round 1
// baseline (3850.148 us; speedup 1.0000x reference)
//
#include <hip/hip_runtime.h>

#define BB 32
#define TT 40
#define TS 39
#define VV 8000
#define EE 50
#define HH 2048
#define NBLK 224

typedef short s16x8 __attribute__((ext_vector_type(8)));
typedef float f32x4 __attribute__((ext_vector_type(4)));

__device__ __forceinline__ float sigmf(float x) { return 1.0f / (1.0f + __expf(-x)); }
__device__ __forceinline__ float tanhf_fast(float x) { return 2.0f / (1.0f + __expf(-2.0f * x)) - 1.0f; }

__device__ __forceinline__ unsigned short f2bf(float x) {
    union { float f; unsigned u; } v; v.f = x;
    unsigned r = v.u + 0x7FFF + ((v.u >> 16) & 1);   // RNE
    return (unsigned short)(r >> 16);
}

// ---------------------------------------------------------------------------
// fp32 -> bf16 weight conversion, 4 elems/thread
// ---------------------------------------------------------------------------
__global__ void convert_kernel(const float* __restrict__ src,
                               unsigned short* __restrict__ dst, int n4) {
    int i = blockIdx.x * 256 + threadIdx.x;
    if (i < n4) {
        float4 v = ((const float4*)src)[i];
        ushort4 o;
        o.x = f2bf(v.x); o.y = f2bf(v.y); o.z = f2bf(v.z); o.w = f2bf(v.w);
        ((ushort4*)dst)[i] = o;
    }
}

// ---------------------------------------------------------------------------
// Phase A: xw[t][b][j] = emb[captions[b][t]] . Wih[j][:] + bih[j] + bhh[j]
// ---------------------------------------------------------------------------
__global__ void embed_proj_kernel(const int* __restrict__ caps,
                                  const float* __restrict__ emb,
                                  const float* __restrict__ Wih,
                                  const float* __restrict__ bih,
                                  const float* __restrict__ bhh,
                                  float* __restrict__ xw) {
    __shared__ float elds[BB][EE];
    int t = blockIdx.y;
    int j = blockIdx.x * 256 + threadIdx.x;
    for (int idx = threadIdx.x; idx < BB * EE; idx += 256) {
        int bl = idx / EE, e = idx - bl * EE;
        elds[bl][e] = emb[(size_t)caps[bl * TT + t] * EE + e];
    }
    __syncthreads();
    float wreg[EE];
#pragma unroll
    for (int e = 0; e < EE; ++e) wreg[e] = Wih[(size_t)j * EE + e];
    float bias = bih[j] + bhh[j];
    for (int bl = 0; bl < BB; ++bl) {
        float acc = bias;
#pragma unroll
        for (int e = 0; e < EE; ++e) acc += wreg[e] * elds[bl][e];
        xw[((size_t)(t * BB + bl)) * (4 * HH) + j] = acc;
    }
}

// ---------------------------------------------------------------------------
// Init: states in [b][k] layout. fp32 masters for c/hg, bf16 copies for MFMA.
// Also zeroes the grid-barrier counter (d_ws is re-poisoned every call).
// ---------------------------------------------------------------------------
__global__ void init_state_kernel(const float* __restrict__ feat,
                                  float* __restrict__ c32, float* __restrict__ hg32,
                                  unsigned short* __restrict__ hbf,
                                  unsigned short* __restrict__ cbf,
                                  unsigned short* __restrict__ hgbf,
                                  unsigned int* __restrict__ bar) {
    int i = blockIdx.x * 256 + threadIdx.x;    // 65536 threads
    float v = feat[i];
    c32[i] = v; hg32[i] = v;
    unsigned short b = f2bf(v);
    hbf[i] = b; cbf[i] = b; hgbf[i] = b;
    if (i == 0) *bar = 0u;
}

// ---------------------------------------------------------------------------
// Device-scope grid barrier. All NBLK blocks are guaranteed co-resident:
// 224 blocks x 16 waves, __launch_bounds__(1024,4) caps VGPR at 128 so every
// CU hosts >=1 block (256 CUs >= 224 blocks). Release on arrive writes back
// the XCD L2; acquire on the successful poll invalidates L1/stale L2 lines
// (G16 fence discipline for cross-XCD visibility).
// ---------------------------------------------------------------------------
__device__ __forceinline__ void grid_sync(unsigned int* bar, unsigned int target) {
    __syncthreads();                 // compiler drains vmcnt before s_barrier
    if (threadIdx.x == 0) {
        __hip_atomic_fetch_add(bar, 1u, __ATOMIC_RELEASE, __HIP_MEMORY_SCOPE_AGENT);
        while (__hip_atomic_load(bar, __ATOMIC_ACQUIRE, __HIP_MEMORY_SCOPE_AGENT) < target)
            __builtin_amdgcn_s_sleep(2);
    }
    __syncthreads();
}

// ---------------------------------------------------------------------------
// Fused recurrence: all 39 steps (step1 + step2 phases) in ONE launch.
// Phase bodies are byte-identical to the previous step1_kernel/step2_kernel.
//
// Phase 1: blocks [0,128): LSTM gates (16-kk strip, 4 gates x 4 K-quarters,
//          16 waves) + fused LSTM activation epilogue.
//          blocks [128,224): GRU gh (64 rows x 4 K-quarters).
// Phase 2: blocks [0,128): gi = cbf @ gWih.T (3 gates x 4 K-quarters,
//          waves 0..11) + fused GRU epilogue. Blocks [128,224) idle.
// Two grid barriers per step (gi needs c_t; LSTM t+1 needs h_t, hg_t).
// MFMA layouts m89/m91-verified, unchanged.
// ---------------------------------------------------------------------------
__global__ __launch_bounds__(1024, 4) void recurrence_kernel(
    const unsigned short* __restrict__ Whh,    // [8192][2048] bf16
    const unsigned short* __restrict__ gWhh,   // [6144][2048] bf16
    const unsigned short* __restrict__ gWih,   // [6144][2048] bf16
    const float* __restrict__ gbhh,            // [6144]
    const float* __restrict__ gbih,            // [6144]
    const float* __restrict__ xw,              // [39][32][8192]
    unsigned short* __restrict__ hbf0,         // [32][2048] ping
    unsigned short* __restrict__ hbf1,         // [32][2048] pong
    unsigned short* __restrict__ hgbf,         // [32][2048]
    unsigned short* __restrict__ cbf,          // [32][2048]
    float* __restrict__ c32,                   // [32][2048]
    float* __restrict__ hg32,                  // [32][2048]
    float* __restrict__ gh,                    // [32][6144]
    unsigned short* __restrict__ hg_all,       // [39*32][2048]
    unsigned int* bar)
{
    __shared__ float lsum[4][4][32][17];
    const int tid = threadIdx.x;
    const int lane = tid & 63;
    const int w = tid >> 6;       // 0..15
    const int g = w >> 2;         // gate (LSTM) / strip (GRU gh)
    const int kh = w & 3;         // K quarter
    const int l15 = lane & 15;
    const int lq = lane >> 4;     // 0..3
    const int kofs = kh * 512 + lq * 8;
    const int bx = blockIdx.x;
    const bool lstm = (bx < 128);

    // phase-1 weight pointer (t-invariant)
    const unsigned short* Brow1 = lstm
        ? Whh  + (size_t)(g * HH + bx * 16 + l15) * HH + kofs
        : gWhh + (size_t)((bx - 128) * 64 + g * 16 + l15) * HH + kofs;

    // phase-2 pointers (t-invariant; clamped so inactive waves/blocks stay in-bounds)
    const int g2  = (w < 12) ? g : 0;
    const int bx2 = lstm ? bx : 0;
    const unsigned short* Brow2  = gWih + (size_t)(g2 * HH + bx2 * 16 + l15) * HH + kofs;
    const unsigned short* A2row0 = cbf + l15 * HH + kofs;
    const unsigned short* A2row1 = A2row0 + 16 * HH;

    unsigned int nbar = 0;

    for (int t = 0; t < TS; ++t) {
        const unsigned short* hin  = (t & 1) ? hbf1 : hbf0;
        unsigned short*       hout = (t & 1) ? hbf0 : hbf1;
        const float* xw_t = xw + (size_t)t * BB * 4 * HH;

        // ---------------- phase 1: LSTM gates + GRU gh ----------------
        {
            const unsigned short* Abase = lstm ? hin : hgbf;
            const unsigned short* Arow0 = Abase + l15 * HH + kofs;
            const unsigned short* Arow1 = Arow0 + 16 * HH;
            f32x4 acc0 = {0.f, 0.f, 0.f, 0.f};
            f32x4 acc1 = {0.f, 0.f, 0.f, 0.f};
#pragma unroll 4
            for (int it = 0; it < 16; ++it) {
                s16x8 bv = *(const s16x8*)(Brow1 + it * 32);
                s16x8 a0 = *(const s16x8*)(Arow0 + it * 32);
                s16x8 a1 = *(const s16x8*)(Arow1 + it * 32);
                acc0 = __builtin_amdgcn_mfma_f32_16x16x32_bf16(a0, bv, acc0, 0, 0, 0);
                acc1 = __builtin_amdgcn_mfma_f32_16x16x32_bf16(a1, bv, acc1, 0, 0, 0);
            }
#pragma unroll
            for (int r = 0; r < 4; ++r) {
                lsum[g][kh][lq * 4 + r][l15]      = acc0[r];   // [gate][ksplit][batch][n]
                lsum[g][kh][16 + lq * 4 + r][l15] = acc1[r];
            }
            __syncthreads();

            if (lstm) {
                if (tid < 512) {
                    int kk0 = bx * 16;
                    int kkl = tid & 15, b = tid >> 4;          // 512 = 32b x 16kk
                    int kk = kk0 + kkl;
                    const float* xwb = xw_t + (size_t)b * 4 * HH;
                    float vi = lsum[0][0][b][kkl] + lsum[0][1][b][kkl] + lsum[0][2][b][kkl] + lsum[0][3][b][kkl] + xwb[kk];
                    float vf = lsum[1][0][b][kkl] + lsum[1][1][b][kkl] + lsum[1][2][b][kkl] + lsum[1][3][b][kkl] + xwb[HH + kk];
                    float vg = lsum[2][0][b][kkl] + lsum[2][1][b][kkl] + lsum[2][2][b][kkl] + lsum[2][3][b][kkl] + xwb[2 * HH + kk];
                    float vo = lsum[3][0][b][kkl] + lsum[3][1][b][kkl] + lsum[3][2][b][kkl] + lsum[3][3][b][kkl] + xwb[3 * HH + kk];
                    int idx = b * HH + kk;
                    float c = sigmf(vf) * c32[idx] + sigmf(vi) * tanhf_fast(vg);
                    float h = sigmf(vo) * tanhf_fast(c);
                    c32[idx] = c;
                    cbf[idx] = f2bf(c);
                    hout[idx] = f2bf(h);
                }
            } else {
                int n0 = (bx - 128) * 64;
                for (int cell = tid; cell < 2048; cell += 1024) {
                    int nl = cell & 63, b = cell >> 6;
                    int s = nl >> 4, n15 = nl & 15;
                    float v = lsum[s][0][b][n15] + lsum[s][1][b][n15] + lsum[s][2][b][n15] + lsum[s][3][b][n15]
                              + gbhh[n0 + nl];
                    gh[b * 3 * HH + n0 + nl] = v;
                }
            }
        }
        grid_sync(bar, ++nbar * NBLK);

        // ---------------- phase 2: gi + GRU epilogue (blocks 0..127) ----------------
        if (lstm) {
            if (w < 12) {
                f32x4 acc0 = {0.f, 0.f, 0.f, 0.f};
                f32x4 acc1 = {0.f, 0.f, 0.f, 0.f};
#pragma unroll 4
                for (int it = 0; it < 16; ++it) {
                    s16x8 bv = *(const s16x8*)(Brow2 + it * 32);
                    s16x8 a0 = *(const s16x8*)(A2row0 + it * 32);
                    s16x8 a1 = *(const s16x8*)(A2row1 + it * 32);
                    acc0 = __builtin_amdgcn_mfma_f32_16x16x32_bf16(a0, bv, acc0, 0, 0, 0);
                    acc1 = __builtin_amdgcn_mfma_f32_16x16x32_bf16(a1, bv, acc1, 0, 0, 0);
                }
#pragma unroll
                for (int r = 0; r < 4; ++r) {
                    lsum[g][kh][lq * 4 + r][l15]      = acc0[r];
                    lsum[g][kh][16 + lq * 4 + r][l15] = acc1[r];
                }
            }
            __syncthreads();

            if (tid < 512) {
                int kkl = tid & 15, b = tid >> 4;
                int kk = bx * 16 + kkl;
                float ri = lsum[0][0][b][kkl] + lsum[0][1][b][kkl] + lsum[0][2][b][kkl] + lsum[0][3][b][kkl] + gbih[kk];
                float zi = lsum[1][0][b][kkl] + lsum[1][1][b][kkl] + lsum[1][2][b][kkl] + lsum[1][3][b][kkl] + gbih[HH + kk];
                float ni = lsum[2][0][b][kkl] + lsum[2][1][b][kkl] + lsum[2][2][b][kkl] + lsum[2][3][b][kkl] + gbih[2 * HH + kk];
                const float* ghb = gh + b * 3 * HH;
                float r = sigmf(ri + ghb[kk]);
                float z = sigmf(zi + ghb[HH + kk]);
                float n = tanhf_fast(ni + r * ghb[2 * HH + kk]);
                int idx = b * HH + kk;
                float hgn = (1.f - z) * n + z * hg32[idx];
                hg32[idx] = hgn;
                unsigned short hb = f2bf(hgn);
                hgbf[idx] = hb;
                hg_all[(size_t)t * BB * HH + idx] = hb;
            }
        }
        grid_sync(bar, ++nbar * NBLK);
    }
}

// ---------------------------------------------------------------------------
// Phase C: out = hg_all @ linW.T + b. bf16 MFMA, 128x128 tile, BK=32.
// ---------------------------------------------------------------------------
__global__ __launch_bounds__(256) void out_gemm_kernel(
    const unsigned short* __restrict__ A,     // [1280][2048] (rows >=1248 junk)
    const unsigned short* __restrict__ Wl,    // [8000][2048] (reads to 8063 ok)
    const float* __restrict__ bl,
    float* __restrict__ out) {
    __shared__ unsigned short As[128][32];
    __shared__ unsigned short Bs[128][32];
    const int tid = threadIdx.x;
    const int lane = tid & 63;
    const int w = tid >> 6;
    const int l15 = lane & 15;
    const int lq = lane >> 4;
    const int mt = blockIdx.x, nt = blockIdx.y;
    const int mq = w >> 1, nq = w & 1;

    const int row0 = tid >> 2, kc0 = (tid & 3) * 8;
    const unsigned short* Ap0 = A + (size_t)(mt * 128 + row0) * HH + kc0;
    const unsigned short* Ap1 = A + (size_t)(mt * 128 + 64 + row0) * HH + kc0;
    const unsigned short* Bp0 = Wl + (size_t)(nt * 128 + row0) * HH + kc0;
    const unsigned short* Bp1 = Wl + (size_t)(nt * 128 + 64 + row0) * HH + kc0;

    f32x4 acc[4][4];
#pragma unroll
    for (int i = 0; i < 4; ++i)
#pragma unroll
        for (int j = 0; j < 4; ++j) acc[i][j] = (f32x4){0.f, 0.f, 0.f, 0.f};

    for (int k0 = 0; k0 < HH; k0 += 32) {
        s16x8 a0v = *(const s16x8*)(Ap0 + k0);
        s16x8 a1v = *(const s16x8*)(Ap1 + k0);
        s16x8 b0v = *(const s16x8*)(Bp0 + k0);
        s16x8 b1v = *(const s16x8*)(Bp1 + k0);
        *(s16x8*)&As[row0][kc0]      = a0v;
        *(s16x8*)&As[64 + row0][kc0] = a1v;
        *(s16x8*)&Bs[row0][kc0]      = b0v;
        *(s16x8*)&Bs[64 + row0][kc0] = b1v;
        __syncthreads();
        s16x8 af[4], bf[4];
#pragma unroll
        for (int i = 0; i < 4; ++i) af[i] = *(const s16x8*)&As[mq * 64 + i * 16 + l15][lq * 8];
#pragma unroll
        for (int j = 0; j < 4; ++j) bf[j] = *(const s16x8*)&Bs[nq * 64 + j * 16 + l15][lq * 8];
#pragma unroll
        for (int i = 0; i < 4; ++i)
#pragma unroll
            for (int j = 0; j < 4; ++j)
                acc[i][j] = __builtin_amdgcn_mfma_f32_16x16x32_bf16(af[i], bf[j], acc[i][j], 0, 0, 0);
        __syncthreads();
    }
#pragma unroll
    for (int j = 0; j < 4; ++j) {
        int n = nt * 128 + nq * 64 + j * 16 + l15;
        float bn = bl[n < VV ? n : VV - 1];
#pragma unroll
        for (int i = 0; i < 4; ++i) {
#pragma unroll
            for (int r = 0; r < 4; ++r) {
                int m = mt * 128 + mq * 64 + i * 16 + lq * 4 + r;
                if (m < TS * BB && n < VV) {
                    int t = m >> 5, b = m & 31;
                    out[((size_t)b * TS + t) * VV + n] = acc[i][j][r] + bn;
                }
            }
        }
    }
}

// ---------------------------------------------------------------------------
extern "C" void kernel_launch(void* const* d_in, const int* in_sizes, int n_in,
                              void* d_out, int out_size, void* d_ws, size_t ws_size,
                              hipStream_t stream) {
    const float* features = (const float*)d_in[0];
    const int*   captions = (const int*)d_in[1];
    const float* emb      = (const float*)d_in[2];
    const float* lstm_Wih = (const float*)d_in[3];
    const float* lstm_bih = (const float*)d_in[4];
    const float* lstm_Whh = (const float*)d_in[5];
    const float* lstm_bhh = (const float*)d_in[6];
    const float* gru_Wih  = (const float*)d_in[7];
    const float* gru_bih  = (const float*)d_in[8];
    const float* gru_Whh  = (const float*)d_in[9];
    const float* gru_bhh  = (const float*)d_in[10];
    const float* lin_W    = (const float*)d_in[11];
    const float* lin_b    = (const float*)d_in[12];
    float* out = (float*)d_out;

    // workspace layout (bf16 section first, then fp32) — ~165 MB total
    unsigned short* us = (unsigned short*)d_ws;
    unsigned short* Whh_bf  = us;                              // 8192*2048
    unsigned short* gWhh_bf = Whh_bf  + (size_t)8192 * HH;     // 6144*2048
    unsigned short* gWih_bf = gWhh_bf + (size_t)6144 * HH;     // 6144*2048
    unsigned short* linW_bf = gWih_bf + (size_t)6144 * HH;     // 8000*2048
    unsigned short* hbf0    = linW_bf + (size_t)VV * HH;
    unsigned short* hbf1    = hbf0 + BB * HH;
    unsigned short* cbf     = hbf1 + BB * HH;
    unsigned short* hgbf    = cbf  + BB * HH;
    unsigned short* hg_all  = hgbf + BB * HH;                  // 1280*2048 (padded)
    float* f32s = (float*)(hg_all + (size_t)1280 * HH);
    float* xw   = f32s;                                        // 39*32*8192
    float* c32  = xw + (size_t)TS * BB * 4 * HH;
    float* hg32 = c32 + BB * HH;
    float* gh   = hg32 + BB * HH;                              // 32*6144
    unsigned int* bar = (unsigned int*)(gh + (size_t)BB * 3 * HH);

    // 1) weight conversion (d_ws is re-poisoned before every call)
    {
        int n4;
        n4 = 8192 * HH / 4;
        convert_kernel<<<(n4 + 255) / 256, 256, 0, stream>>>(lstm_Whh, Whh_bf, n4);
        n4 = 6144 * HH / 4;
        convert_kernel<<<(n4 + 255) / 256, 256, 0, stream>>>(gru_Whh, gWhh_bf, n4);
        convert_kernel<<<(n4 + 255) / 256, 256, 0, stream>>>(gru_Wih, gWih_bf, n4);
        n4 = VV * HH / 4;
        convert_kernel<<<(n4 + 255) / 256, 256, 0, stream>>>(lin_W, linW_bf, n4);
    }

    // 2) precompute x-side gate biases for all steps
    embed_proj_kernel<<<dim3(4 * HH / 256, TS), 256, 0, stream>>>(
        captions, emb, lstm_Wih, lstm_bih, lstm_bhh, xw);

    // 3) init states + zero grid barrier
    init_state_kernel<<<(BB * HH) / 256, 256, 0, stream>>>(
        features, c32, hg32, hbf0, cbf, hgbf, bar);

    // 4) fused recurrence: ONE launch, 78 grid barriers instead of 78 launches
    recurrence_kernel<<<NBLK, 1024, 0, stream>>>(
        Whh_bf, gWhh_bf, gWih_bf, gru_bhh, gru_bih, xw,
        hbf0, hbf1, hgbf, cbf, c32, hg32, gh, hg_all, bar);

    // 5) output projection
    out_gemm_kernel<<<dim3((TS * BB + 127) / 128, (VV + 127) / 128), 256, 0, stream>>>(
        hg_all, linW_bf, lin_b, out);
}

// Round 2
// 3371.032 us; speedup vs baseline: 1.1421x; 1.1421x over previous
//
#include <hip/hip_runtime.h>

#define BB 32
#define TT 40
#define TS 39
#define VV 8000
#define EE 50
#define HH 2048
#define NBLK 256

typedef short s16x8 __attribute__((ext_vector_type(8)));
typedef float f32x4 __attribute__((ext_vector_type(4)));

__device__ __forceinline__ float sigmf(float x) { return 1.0f / (1.0f + __expf(-x)); }
__device__ __forceinline__ float tanhf_fast(float x) { return 2.0f / (1.0f + __expf(-2.0f * x)) - 1.0f; }

__device__ __forceinline__ unsigned short f2bf(float x) {
    union { float f; unsigned u; } v; v.f = x;
    unsigned r = v.u + 0x7FFF + ((v.u >> 16) & 1);   // RNE
    return (unsigned short)(r >> 16);
}

// 8 consecutive fp32 -> s16x8 bf16 fragment (32B-aligned source)
__device__ __forceinline__ s16x8 cvt8(const float* p) {
    float4 a = *(const float4*)p;
    float4 b = *(const float4*)(p + 4);
    s16x8 r;
    r[0] = (short)f2bf(a.x); r[1] = (short)f2bf(a.y);
    r[2] = (short)f2bf(a.z); r[3] = (short)f2bf(a.w);
    r[4] = (short)f2bf(b.x); r[5] = (short)f2bf(b.y);
    r[6] = (short)f2bf(b.z); r[7] = (short)f2bf(b.w);
    return r;
}

// ---------------------------------------------------------------------------
// fp32 -> bf16 conversion (lin_W only now), 4 elems/thread
// ---------------------------------------------------------------------------
__global__ void convert_kernel(const float* __restrict__ src,
                               unsigned short* __restrict__ dst, int n4) {
    int i = blockIdx.x * 256 + threadIdx.x;
    if (i < n4) {
        float4 v = ((const float4*)src)[i];
        ushort4 o;
        o.x = f2bf(v.x); o.y = f2bf(v.y); o.z = f2bf(v.z); o.w = f2bf(v.w);
        ((ushort4*)dst)[i] = o;
    }
}

// ---------------------------------------------------------------------------
// Phase A: xw[t][b][j] = emb[captions[b][t]] . Wih[j][:] + bih[j] + bhh[j]
// ---------------------------------------------------------------------------
__global__ void embed_proj_kernel(const int* __restrict__ caps,
                                  const float* __restrict__ emb,
                                  const float* __restrict__ Wih,
                                  const float* __restrict__ bih,
                                  const float* __restrict__ bhh,
                                  float* __restrict__ xw) {
    __shared__ float elds[BB][EE];
    int t = blockIdx.y;
    int j = blockIdx.x * 256 + threadIdx.x;
    for (int idx = threadIdx.x; idx < BB * EE; idx += 256) {
        int bl = idx / EE, e = idx - bl * EE;
        elds[bl][e] = emb[(size_t)caps[bl * TT + t] * EE + e];
    }
    __syncthreads();
    float wreg[EE];
#pragma unroll
    for (int e = 0; e < EE; ++e) wreg[e] = Wih[(size_t)j * EE + e];
    float bias = bih[j] + bhh[j];
    for (int bl = 0; bl < BB; ++bl) {
        float acc = bias;
#pragma unroll
        for (int e = 0; e < EE; ++e) acc += wreg[e] * elds[bl][e];
        xw[((size_t)(t * BB + bl)) * (4 * HH) + j] = acc;
    }
}

// ---------------------------------------------------------------------------
// Init: bf16 state copies (h, hg) + zero the grid-barrier counter.
// (c/hg fp32 masters live in recurrence-kernel registers; cbf is written by
//  the P1 epilogue before anyone reads it.)
// ---------------------------------------------------------------------------
__global__ void init_state_kernel(const float* __restrict__ feat,
                                  unsigned short* __restrict__ hbf,
                                  unsigned short* __restrict__ hgbf,
                                  unsigned int* __restrict__ bar) {
    int i = blockIdx.x * 256 + threadIdx.x;    // 65536 threads
    unsigned short b = f2bf(feat[i]);
    hbf[i] = b; hgbf[i] = b;
    if (i == 0) *bar = 0u;
}

// ---------------------------------------------------------------------------
// Grid barrier, fence-storm-free: RELAXED polling (no per-poll buffer_inv),
// one RELEASE on arrive (writes back XCD L2), one ACQUIRE fence on exit
// (invalidates L1/L2 once). 256 blocks, 1/CU -> co-residency guaranteed.
// ---------------------------------------------------------------------------
__device__ __forceinline__ void grid_sync(unsigned int* bar, unsigned int target) {
    __syncthreads();                 // each wave drains vmcnt -> stores in L2
    if (threadIdx.x == 0) {
        __hip_atomic_fetch_add(bar, 1u, __ATOMIC_RELEASE, __HIP_MEMORY_SCOPE_AGENT);
        while (__hip_atomic_load(bar, __ATOMIC_RELAXED, __HIP_MEMORY_SCOPE_AGENT) < target)
            __builtin_amdgcn_s_sleep(1);
    }
    __syncthreads();
    __builtin_amdgcn_fence(__ATOMIC_ACQUIRE, "agent");
}

// ---------------------------------------------------------------------------
// Persistent recurrence, weights register-resident for all 39 steps.
// 256 blocks x 512 threads (8 waves). Block = (16-cell strip s=bx>>1) x
// (batch half bh=bx&1). Wave w owns K-slice [w*256, w*256+256).
// Per wave: 10 weight tiles x 8 ksteps x s16x8 = 320 VGPRs (one-time fp32
// load + in-reg bf16 convert). P1 = LSTM(4 tiles) + gh(3); P2 = gi(3).
// Cross-wave K-reduction via LDS (verified lsum pattern, m=batch n=cell).
// gh parked in LDS across barrier1; c/hg fp32 masters in registers.
// 2 grid barriers per step (last one elided).
// ---------------------------------------------------------------------------
__global__ __launch_bounds__(512, 1) void recurrence_kernel(
    const float* __restrict__ Whh,     // [8192][2048] fp32
    const float* __restrict__ gWhh,    // [6144][2048] fp32
    const float* __restrict__ gWih,    // [6144][2048] fp32
    const float* __restrict__ gbhh,    // [6144]
    const float* __restrict__ gbih,    // [6144]
    const float* __restrict__ feat,    // [32][2048]
    const float* __restrict__ xw,      // [39][32][8192]
    unsigned short* __restrict__ hbf0, // [32][2048] ping
    unsigned short* __restrict__ hbf1, // [32][2048] pong
    unsigned short* __restrict__ hgbf, // [32][2048]
    unsigned short* __restrict__ cbf,  // [32][2048]
    unsigned short* __restrict__ hg_all, // [39*32][2048]
    unsigned int* bar)
{
    __shared__ float lsum[7][8][16][16];   // [tile][wave][m=batch][n=cell]
    __shared__ float ghs[3][256];          // gh + bhh, persists P1 -> P2

    const int tid = threadIdx.x;
    const int lane = tid & 63;
    const int w = tid >> 6;          // 0..7
    const int l15 = lane & 15;
    const int lq = lane >> 4;        // 0..3
    const int bx = blockIdx.x;
    const int bh = bx & 1;
    const int kk0 = (bx >> 1) * 16;
    const int koff = w * 256 + lq * 8;

    // ---- one-time: weights -> registers (fp32 read, bf16 in-reg) ----
    s16x8 wL[4][8], wG[3][8], wI[3][8];
    {
        const size_t rb = (size_t)(kk0 + l15) * HH + koff;
#pragma unroll
        for (int g = 0; g < 4; ++g)
#pragma unroll
            for (int it = 0; it < 8; ++it)
                wL[g][it] = cvt8(Whh + rb + (size_t)g * HH * HH + it * 32);
#pragma unroll
        for (int u = 0; u < 3; ++u)
#pragma unroll
            for (int it = 0; it < 8; ++it) {
                wG[u][it] = cvt8(gWhh + rb + (size_t)u * HH * HH + it * 32);
                wI[u][it] = cvt8(gWih + rb + (size_t)u * HH * HH + it * 32);
            }
    }

    // ---- per-element master state + biases (epilogue threads 0..255) ----
    const int cell = tid & 15;
    const int bq = tid >> 4;                 // active when < 16
    const int brow = bh * 16 + bq;
    const int gidx = brow * HH + kk0 + cell; // only accessed when tid<256
    float c_m = 0.f, hg_m = 0.f;
    float gbh0 = 0.f, gbh1 = 0.f, gbh2 = 0.f, gbi0 = 0.f, gbi1 = 0.f, gbi2 = 0.f;
    if (tid < 256) {
        float v = feat[gidx];
        c_m = v; hg_m = v;
        gbh0 = gbhh[kk0 + cell]; gbh1 = gbhh[HH + kk0 + cell]; gbh2 = gbhh[2 * HH + kk0 + cell];
        gbi0 = gbih[kk0 + cell]; gbi1 = gbih[HH + kk0 + cell]; gbi2 = gbih[2 * HH + kk0 + cell];
    }

    unsigned int nbar = 0;
    for (int t = 0; t < TS; ++t) {
        const unsigned short* hin  = (t & 1) ? hbf1 : hbf0;
        unsigned short*       hout = (t & 1) ? hbf0 : hbf1;

        // ---------------- P1: LSTM gates + GRU gh ----------------
        {
            const unsigned short* Ah = hin  + (size_t)(bh * 16 + l15) * HH + koff;
            const unsigned short* Ag = hgbf + (size_t)(bh * 16 + l15) * HH + koff;
            f32x4 acc[7];
#pragma unroll
            for (int q = 0; q < 7; ++q) acc[q] = (f32x4){0.f, 0.f, 0.f, 0.f};
#pragma unroll
            for (int it = 0; it < 8; ++it) {
                s16x8 ah = *(const s16x8*)(Ah + it * 32);
                s16x8 ag = *(const s16x8*)(Ag + it * 32);
                acc[0] = __builtin_amdgcn_mfma_f32_16x16x32_bf16(ah, wL[0][it], acc[0], 0, 0, 0);
                acc[1] = __builtin_amdgcn_mfma_f32_16x16x32_bf16(ah, wL[1][it], acc[1], 0, 0, 0);
                acc[2] = __builtin_amdgcn_mfma_f32_16x16x32_bf16(ah, wL[2][it], acc[2], 0, 0, 0);
                acc[3] = __builtin_amdgcn_mfma_f32_16x16x32_bf16(ah, wL[3][it], acc[3], 0, 0, 0);
                acc[4] = __builtin_amdgcn_mfma_f32_16x16x32_bf16(ag, wG[0][it], acc[4], 0, 0, 0);
                acc[5] = __builtin_amdgcn_mfma_f32_16x16x32_bf16(ag, wG[1][it], acc[5], 0, 0, 0);
                acc[6] = __builtin_amdgcn_mfma_f32_16x16x32_bf16(ag, wG[2][it], acc[6], 0, 0, 0);
            }
#pragma unroll
            for (int q = 0; q < 7; ++q)
#pragma unroll
                for (int r = 0; r < 4; ++r)
                    lsum[q][w][lq * 4 + r][l15] = acc[q][r];
        }
        __syncthreads();
        if (tid < 256) {
            float s0 = 0.f, s1 = 0.f, s2 = 0.f, s3 = 0.f, s4 = 0.f, s5 = 0.f, s6 = 0.f;
#pragma unroll
            for (int wv = 0; wv < 8; ++wv) {
                s0 += lsum[0][wv][bq][cell];
                s1 += lsum[1][wv][bq][cell];
                s2 += lsum[2][wv][bq][cell];
                s3 += lsum[3][wv][bq][cell];
                s4 += lsum[4][wv][bq][cell];
                s5 += lsum[5][wv][bq][cell];
                s6 += lsum[6][wv][bq][cell];
            }
            const float* xwb = xw + ((size_t)t * BB + brow) * 4 * HH + kk0 + cell;
            float c = sigmf(s1 + xwb[HH]) * c_m + sigmf(s0 + xwb[0]) * tanhf_fast(s2 + xwb[2 * HH]);
            float h = sigmf(s3 + xwb[3 * HH]) * tanhf_fast(c);
            c_m = c;
            cbf[gidx]  = f2bf(c);
            hout[gidx] = f2bf(h);
            ghs[0][tid] = s4 + gbh0;
            ghs[1][tid] = s5 + gbh1;
            ghs[2][tid] = s6 + gbh2;
        }
        grid_sync(bar, ++nbar * NBLK);     // c visible everywhere

        // ---------------- P2: gi + GRU epilogue ----------------
        {
            const unsigned short* Ac = cbf + (size_t)(bh * 16 + l15) * HH + koff;
            f32x4 acc[3];
#pragma unroll
            for (int q = 0; q < 3; ++q) acc[q] = (f32x4){0.f, 0.f, 0.f, 0.f};
#pragma unroll
            for (int it = 0; it < 8; ++it) {
                s16x8 ac = *(const s16x8*)(Ac + it * 32);
                acc[0] = __builtin_amdgcn_mfma_f32_16x16x32_bf16(ac, wI[0][it], acc[0], 0, 0, 0);
                acc[1] = __builtin_amdgcn_mfma_f32_16x16x32_bf16(ac, wI[1][it], acc[1], 0, 0, 0);
                acc[2] = __builtin_amdgcn_mfma_f32_16x16x32_bf16(ac, wI[2][it], acc[2], 0, 0, 0);
            }
#pragma unroll
            for (int q = 0; q < 3; ++q)
#pragma unroll
                for (int r = 0; r < 4; ++r)
                    lsum[q][w][lq * 4 + r][l15] = acc[q][r];
        }
        __syncthreads();
        if (tid < 256) {
            float s0 = 0.f, s1 = 0.f, s2 = 0.f;
#pragma unroll
            for (int wv = 0; wv < 8; ++wv) {
                s0 += lsum[0][wv][bq][cell];
                s1 += lsum[1][wv][bq][cell];
                s2 += lsum[2][wv][bq][cell];
            }
            float r = sigmf(s0 + gbi0 + ghs[0][tid]);
            float z = sigmf(s1 + gbi1 + ghs[1][tid]);
            float n = tanhf_fast(s2 + gbi2 + r * ghs[2][tid]);
            float hg = (1.f - z) * n + z * hg_m;
            hg_m = hg;
            unsigned short hb = f2bf(hg);
            hgbf[gidx] = hb;
            hg_all[(size_t)t * BB * HH + gidx] = hb;
        }
        if (t < TS - 1)
            grid_sync(bar, ++nbar * NBLK); // h, hg visible for next step
    }
}

// ---------------------------------------------------------------------------
// Phase C: out = hg_all @ linW.T + b. bf16 MFMA, 128x128 tile, BK=32.
// ---------------------------------------------------------------------------
__global__ __launch_bounds__(256) void out_gemm_kernel(
    const unsigned short* __restrict__ A,     // [1280][2048] (rows >=1248 junk)
    const unsigned short* __restrict__ Wl,    // [8000][2048] (reads to 8063 ok)
    const float* __restrict__ bl,
    float* __restrict__ out) {
    __shared__ unsigned short As[128][32];
    __shared__ unsigned short Bs[128][32];
    const int tid = threadIdx.x;
    const int lane = tid & 63;
    const int w = tid >> 6;
    const int l15 = lane & 15;
    const int lq = lane >> 4;
    const int mt = blockIdx.x, nt = blockIdx.y;
    const int mq = w >> 1, nq = w & 1;

    const int row0 = tid >> 2, kc0 = (tid & 3) * 8;
    const unsigned short* Ap0 = A + (size_t)(mt * 128 + row0) * HH + kc0;
    const unsigned short* Ap1 = A + (size_t)(mt * 128 + 64 + row0) * HH + kc0;
    const unsigned short* Bp0 = Wl + (size_t)(nt * 128 + row0) * HH + kc0;
    const unsigned short* Bp1 = Wl + (size_t)(nt * 128 + 64 + row0) * HH + kc0;

    f32x4 acc[4][4];
#pragma unroll
    for (int i = 0; i < 4; ++i)
#pragma unroll
        for (int j = 0; j < 4; ++j) acc[i][j] = (f32x4){0.f, 0.f, 0.f, 0.f};

    for (int k0 = 0; k0 < HH; k0 += 32) {
        s16x8 a0v = *(const s16x8*)(Ap0 + k0);
        s16x8 a1v = *(const s16x8*)(Ap1 + k0);
        s16x8 b0v = *(const s16x8*)(Bp0 + k0);
        s16x8 b1v = *(const s16x8*)(Bp1 + k0);
        *(s16x8*)&As[row0][kc0]      = a0v;
        *(s16x8*)&As[64 + row0][kc0] = a1v;
        *(s16x8*)&Bs[row0][kc0]      = b0v;
        *(s16x8*)&Bs[64 + row0][kc0] = b1v;
        __syncthreads();
        s16x8 af[4], bf[4];
#pragma unroll
        for (int i = 0; i < 4; ++i) af[i] = *(const s16x8*)&As[mq * 64 + i * 16 + l15][lq * 8];
#pragma unroll
        for (int j = 0; j < 4; ++j) bf[j] = *(const s16x8*)&Bs[nq * 64 + j * 16 + l15][lq * 8];
#pragma unroll
        for (int i = 0; i < 4; ++i)
#pragma unroll
            for (int j = 0; j < 4; ++j)
                acc[i][j] = __builtin_amdgcn_mfma_f32_16x16x32_bf16(af[i], bf[j], acc[i][j], 0, 0, 0);
        __syncthreads();
    }
#pragma unroll
    for (int j = 0; j < 4; ++j) {
        int n = nt * 128 + nq * 64 + j * 16 + l15;
        float bn = bl[n < VV ? n : VV - 1];
#pragma unroll
        for (int i = 0; i < 4; ++i) {
#pragma unroll
            for (int r = 0; r < 4; ++r) {
                int m = mt * 128 + mq * 64 + i * 16 + lq * 4 + r;
                if (m < TS * BB && n < VV) {
                    int t = m >> 5, b = m & 31;
                    out[((size_t)b * TS + t) * VV + n] = acc[i][j][r] + bn;
                }
            }
        }
    }
}

// ---------------------------------------------------------------------------
extern "C" void kernel_launch(void* const* d_in, const int* in_sizes, int n_in,
                              void* d_out, int out_size, void* d_ws, size_t ws_size,
                              hipStream_t stream) {
    const float* features = (const float*)d_in[0];
    const int*   captions = (const int*)d_in[1];
    const float* emb      = (const float*)d_in[2];
    const float* lstm_Wih = (const float*)d_in[3];
    const float* lstm_bih = (const float*)d_in[4];
    const float* lstm_Whh = (const float*)d_in[5];
    const float* lstm_bhh = (const float*)d_in[6];
    const float* gru_Wih  = (const float*)d_in[7];
    const float* gru_bih  = (const float*)d_in[8];
    const float* gru_Whh  = (const float*)d_in[9];
    const float* gru_bhh  = (const float*)d_in[10];
    const float* lin_W    = (const float*)d_in[11];
    const float* lin_b    = (const float*)d_in[12];
    float* out = (float*)d_out;

    // workspace layout
    unsigned short* us = (unsigned short*)d_ws;
    unsigned short* linW_bf = us;                              // 8000*2048
    unsigned short* hbf0    = linW_bf + (size_t)VV * HH;       // (out_gemm may
    unsigned short* hbf1    = hbf0 + BB * HH;                  //  over-read into
    unsigned short* cbf     = hbf1 + BB * HH;                  //  these - benign)
    unsigned short* hgbf    = cbf  + BB * HH;
    unsigned short* hg_all  = hgbf + BB * HH;                  // 1280*2048 (padded)
    float* xw = (float*)(hg_all + (size_t)1280 * HH);          // 39*32*8192
    unsigned int* bar = (unsigned int*)(xw + (size_t)TS * BB * 4 * HH);

    // 1) bf16 convert for the output GEMM weight only
    convert_kernel<<<(VV * HH / 4 + 255) / 256, 256, 0, stream>>>(lin_W, linW_bf, VV * HH / 4);

    // 2) precompute x-side gate biases for all steps
    embed_proj_kernel<<<dim3(4 * HH / 256, TS), 256, 0, stream>>>(
        captions, emb, lstm_Wih, lstm_bih, lstm_bhh, xw);

    // 3) init bf16 states + zero grid barrier
    init_state_kernel<<<(BB * HH) / 256, 256, 0, stream>>>(features, hbf0, hgbf, bar);

    // 4) persistent recurrence: weights live in registers for all 39 steps
    recurrence_kernel<<<NBLK, 512, 0, stream>>>(
        lstm_Whh, gru_Whh, gru_Wih, gru_bhh, gru_bih, features, xw,
        hbf0, hbf1, hgbf, cbf, hg_all, bar);

    // 5) output projection
    out_gemm_kernel<<<dim3((TS * BB + 127) / 128, (VV + 127) / 128), 256, 0, stream>>>(
        hg_all, linW_bf, lin_b, out);
}

// Round 3
// 2867.288 us; speedup vs baseline: 1.3428x; 1.1757x over previous
//
#include <hip/hip_runtime.h>

#define BB 32
#define TT 40
#define TS 39
#define VV 8000
#define EE 50
#define HH 2048
#define NBLK 256

typedef short s16x8 __attribute__((ext_vector_type(8)));
typedef float f32x4 __attribute__((ext_vector_type(4)));

__device__ __forceinline__ float sigmf(float x) { return 1.0f / (1.0f + __expf(-x)); }
__device__ __forceinline__ float tanhf_fast(float x) { return 2.0f / (1.0f + __expf(-2.0f * x)) - 1.0f; }

__device__ __forceinline__ unsigned short f2bf(float x) {
    union { float f; unsigned u; } v; v.f = x;
    unsigned r = v.u + 0x7FFF + ((v.u >> 16) & 1);   // RNE
    return (unsigned short)(r >> 16);
}

// 8 consecutive fp32 -> s16x8 bf16 fragment (32B-aligned source)
__device__ __forceinline__ s16x8 cvt8(const float* p) {
    float4 a = *(const float4*)p;
    float4 b = *(const float4*)(p + 4);
    s16x8 r;
    r[0] = (short)f2bf(a.x); r[1] = (short)f2bf(a.y);
    r[2] = (short)f2bf(a.z); r[3] = (short)f2bf(a.w);
    r[4] = (short)f2bf(b.x); r[5] = (short)f2bf(b.y);
    r[6] = (short)f2bf(b.z); r[7] = (short)f2bf(b.w);
    return r;
}

// ---------------------------------------------------------------------------
// fp32 -> bf16 conversion (lin_W only), 4 elems/thread
// ---------------------------------------------------------------------------
__global__ void convert_kernel(const float* __restrict__ src,
                               unsigned short* __restrict__ dst, int n4) {
    int i = blockIdx.x * 256 + threadIdx.x;
    if (i < n4) {
        float4 v = ((const float4*)src)[i];
        ushort4 o;
        o.x = f2bf(v.x); o.y = f2bf(v.y); o.z = f2bf(v.z); o.w = f2bf(v.w);
        ((ushort4*)dst)[i] = o;
    }
}

// ---------------------------------------------------------------------------
// Phase A: xw[t][b][j] = emb[captions[b][t]] . Wih[j][:] + bih[j] + bhh[j]
// ---------------------------------------------------------------------------
__global__ void embed_proj_kernel(const int* __restrict__ caps,
                                  const float* __restrict__ emb,
                                  const float* __restrict__ Wih,
                                  const float* __restrict__ bih,
                                  const float* __restrict__ bhh,
                                  float* __restrict__ xw) {
    __shared__ float elds[BB][EE];
    int t = blockIdx.y;
    int j = blockIdx.x * 256 + threadIdx.x;
    for (int idx = threadIdx.x; idx < BB * EE; idx += 256) {
        int bl = idx / EE, e = idx - bl * EE;
        elds[bl][e] = emb[(size_t)caps[bl * TT + t] * EE + e];
    }
    __syncthreads();
    float wreg[EE];
#pragma unroll
    for (int e = 0; e < EE; ++e) wreg[e] = Wih[(size_t)j * EE + e];
    float bias = bih[j] + bhh[j];
    for (int bl = 0; bl < BB; ++bl) {
        float acc = bias;
#pragma unroll
        for (int e = 0; e < EE; ++e) acc += wreg[e] * elds[bl][e];
        xw[((size_t)(t * BB + bl)) * (4 * HH) + j] = acc;
    }
}

// ---------------------------------------------------------------------------
// Init: bf16 state copies (h, hg) + zero the grid-barrier counter.
// ---------------------------------------------------------------------------
__global__ void init_state_kernel(const float* __restrict__ feat,
                                  unsigned short* __restrict__ hbf,
                                  unsigned short* __restrict__ hgbf,
                                  unsigned int* __restrict__ bar) {
    int i = blockIdx.x * 256 + threadIdx.x;    // 65536 threads
    unsigned short b = f2bf(feat[i]);
    hbf[i] = b; hgbf[i] = b;
    if (i == 0) *bar = 0u;
}

// ---------------------------------------------------------------------------
// Grid barrier: RELAXED polling, one RELEASE on arrive, one ACQUIRE fence on
// exit. 256 blocks, 1/CU -> co-residency guaranteed. (Passed correctness in
// rounds 1-2.)
// ---------------------------------------------------------------------------
__device__ __forceinline__ void grid_sync(unsigned int* bar, unsigned int target) {
    __syncthreads();
    if (threadIdx.x == 0) {
        __hip_atomic_fetch_add(bar, 1u, __ATOMIC_RELEASE, __HIP_MEMORY_SCOPE_AGENT);
        while (__hip_atomic_load(bar, __ATOMIC_RELAXED, __HIP_MEMORY_SCOPE_AGENT) < target)
            __builtin_amdgcn_s_sleep(1);
    }
    __syncthreads();
    __builtin_amdgcn_fence(__ATOMIC_ACQUIRE, "agent");
}

// ---------------------------------------------------------------------------
// Persistent recurrence, weights register-resident for all 39 steps.
// 256 blocks = 128 strips x 2 roles; 512 threads (8 waves); 1 block/CU.
// Wave w owns K-slice [w*256, w*256+256) -> 8 ksteps of 32.
// Each wave holds FIVE weight tiles x 8 ksteps = 40 s16x8 = 160 VGPRs:
//   role 0: LSTM {i,f,g,o} + GRU gh_r      (P1: 5 tiles x 2 batch halves)
//   role 1: GRU {gh_z, gh_n} (P1) + gi {r,z,n} (P2, A = c_t)
// Budget/wave: 160 wt + 40 acc + ~30 misc = ~230 <= 256 (launch_bounds(512,2)).
// Cross-wave K-reduction via LDS lsum; role-1's gh_z/gh_n sums persist in
// lsum[0..1] across the mid barrier (P2 writes only lsum[2..4]).
// gh_r (+bias) crosses roles via gh0_g global buffer at the mid barrier.
// c (role 0) and hg (role 1) fp32 masters live in epilogue-thread registers.
// ---------------------------------------------------------------------------
__global__ __launch_bounds__(512, 2) void recurrence_kernel(
    const float* __restrict__ Whh,     // [8192][2048] fp32
    const float* __restrict__ gWhh,    // [6144][2048] fp32
    const float* __restrict__ gWih,    // [6144][2048] fp32
    const float* __restrict__ gbhh,    // [6144]
    const float* __restrict__ gbih,    // [6144]
    const float* __restrict__ feat,    // [32][2048]
    const float* __restrict__ xw,      // [39][32][8192]
    unsigned short* __restrict__ hbf0, // [32][2048] ping
    unsigned short* __restrict__ hbf1, // [32][2048] pong
    unsigned short* __restrict__ hgbf, // [32][2048]
    unsigned short* __restrict__ cbf,  // [32][2048]
    float* __restrict__ gh0_g,         // [128][512] gh_r + bias, role0 -> role1
    unsigned short* __restrict__ hg_all, // [39*32][2048]
    unsigned int* bar)
{
    __shared__ float lsum[5][8][32][17];   // [tile][wave][m=batch][n=cell] 87KB

    const int tid = threadIdx.x;
    const int lane = tid & 63;
    const int w = tid >> 6;          // 0..7
    const int l15 = lane & 15;
    const int lq = lane >> 4;        // 0..3
    const int bx = blockIdx.x;
    const int role = bx & 1;
    const int strip = bx >> 1;
    const int kk0 = strip * 16;
    const int koff = w * 256 + lq * 8;

    // ---- one-time: 5 weight tiles -> registers (fp32 read, bf16 in-reg) ----
    const size_t rstep = (size_t)HH * HH;
    const size_t rowoff = (size_t)(kk0 + l15) * HH + koff;
    const float* wrow[5];
    if (role == 0) {
        wrow[0] = Whh + rowoff;                 // LSTM i
        wrow[1] = Whh + rstep + rowoff;         // LSTM f
        wrow[2] = Whh + 2 * rstep + rowoff;     // LSTM g
        wrow[3] = Whh + 3 * rstep + rowoff;     // LSTM o
        wrow[4] = gWhh + rowoff;                // GRU gh_r
    } else {
        wrow[0] = gWhh + rstep + rowoff;        // GRU gh_z
        wrow[1] = gWhh + 2 * rstep + rowoff;    // GRU gh_n
        wrow[2] = gWih + rowoff;                // GRU gi_r
        wrow[3] = gWih + rstep + rowoff;        // GRU gi_z
        wrow[4] = gWih + 2 * rstep + rowoff;    // GRU gi_n
    }
    s16x8 w5[5][8];
#pragma unroll
    for (int q = 0; q < 5; ++q)
#pragma unroll
        for (int it = 0; it < 8; ++it)
            w5[q][it] = cvt8(wrow[q] + it * 32);

    // ---- per-element master state + biases (all 512 threads: 32b x 16cell) ----
    const int cell = tid & 15;
    const int bq = tid >> 4;                 // 0..31
    const int gidx = bq * HH + kk0 + cell;
    float st_m;                              // role0: c master, role1: hg master
    float b0 = 0.f, b1 = 0.f, b2 = 0.f, b3 = 0.f;
    {
        st_m = feat[gidx];
        if (role == 0) {
            b0 = gbhh[kk0 + cell];                    // bhh_r (goes with gh_r)
        } else {
            b0 = gbih[kk0 + cell];                    // bih_r
            b1 = gbih[HH + kk0 + cell] + gbhh[HH + kk0 + cell];      // z biases
            b2 = gbih[2 * HH + kk0 + cell];           // bih_n
            b3 = gbhh[2 * HH + kk0 + cell];           // bhh_n (inside r*)
        }
    }

    unsigned int nbar = 0;
    for (int t = 0; t < TS; ++t) {
        const unsigned short* hin  = (t & 1) ? hbf1 : hbf0;
        unsigned short*       hout = (t & 1) ? hbf0 : hbf1;

        // ---------------- P1 MFMAs ----------------
        {
            f32x4 acc[5][2];
#pragma unroll
            for (int q = 0; q < 5; ++q) {
                acc[q][0] = (f32x4){0.f, 0.f, 0.f, 0.f};
                acc[q][1] = (f32x4){0.f, 0.f, 0.f, 0.f};
            }
            if (role == 0) {
                const unsigned short* Ah = hin  + (size_t)l15 * HH + koff;
                const unsigned short* Ag = hgbf + (size_t)l15 * HH + koff;
#pragma unroll
                for (int it = 0; it < 8; ++it) {
                    s16x8 ah0 = *(const s16x8*)(Ah + it * 32);
                    s16x8 ah1 = *(const s16x8*)(Ah + 16 * HH + it * 32);
                    s16x8 ag0 = *(const s16x8*)(Ag + it * 32);
                    s16x8 ag1 = *(const s16x8*)(Ag + 16 * HH + it * 32);
                    acc[0][0] = __builtin_amdgcn_mfma_f32_16x16x32_bf16(ah0, w5[0][it], acc[0][0], 0, 0, 0);
                    acc[0][1] = __builtin_amdgcn_mfma_f32_16x16x32_bf16(ah1, w5[0][it], acc[0][1], 0, 0, 0);
                    acc[1][0] = __builtin_amdgcn_mfma_f32_16x16x32_bf16(ah0, w5[1][it], acc[1][0], 0, 0, 0);
                    acc[1][1] = __builtin_amdgcn_mfma_f32_16x16x32_bf16(ah1, w5[1][it], acc[1][1], 0, 0, 0);
                    acc[2][0] = __builtin_amdgcn_mfma_f32_16x16x32_bf16(ah0, w5[2][it], acc[2][0], 0, 0, 0);
                    acc[2][1] = __builtin_amdgcn_mfma_f32_16x16x32_bf16(ah1, w5[2][it], acc[2][1], 0, 0, 0);
                    acc[3][0] = __builtin_amdgcn_mfma_f32_16x16x32_bf16(ah0, w5[3][it], acc[3][0], 0, 0, 0);
                    acc[3][1] = __builtin_amdgcn_mfma_f32_16x16x32_bf16(ah1, w5[3][it], acc[3][1], 0, 0, 0);
                    acc[4][0] = __builtin_amdgcn_mfma_f32_16x16x32_bf16(ag0, w5[4][it], acc[4][0], 0, 0, 0);
                    acc[4][1] = __builtin_amdgcn_mfma_f32_16x16x32_bf16(ag1, w5[4][it], acc[4][1], 0, 0, 0);
                }
#pragma unroll
                for (int q = 0; q < 5; ++q)
#pragma unroll
                    for (int r = 0; r < 4; ++r) {
                        lsum[q][w][lq * 4 + r][l15]      = acc[q][0][r];
                        lsum[q][w][16 + lq * 4 + r][l15] = acc[q][1][r];
                    }
            } else {
                const unsigned short* Ag = hgbf + (size_t)l15 * HH + koff;
#pragma unroll
                for (int it = 0; it < 8; ++it) {
                    s16x8 ag0 = *(const s16x8*)(Ag + it * 32);
                    s16x8 ag1 = *(const s16x8*)(Ag + 16 * HH + it * 32);
                    acc[0][0] = __builtin_amdgcn_mfma_f32_16x16x32_bf16(ag0, w5[0][it], acc[0][0], 0, 0, 0);
                    acc[0][1] = __builtin_amdgcn_mfma_f32_16x16x32_bf16(ag1, w5[0][it], acc[0][1], 0, 0, 0);
                    acc[1][0] = __builtin_amdgcn_mfma_f32_16x16x32_bf16(ag0, w5[1][it], acc[1][0], 0, 0, 0);
                    acc[1][1] = __builtin_amdgcn_mfma_f32_16x16x32_bf16(ag1, w5[1][it], acc[1][1], 0, 0, 0);
                }
#pragma unroll
                for (int q = 0; q < 2; ++q)
#pragma unroll
                    for (int r = 0; r < 4; ++r) {
                        lsum[q][w][lq * 4 + r][l15]      = acc[q][0][r];
                        lsum[q][w][16 + lq * 4 + r][l15] = acc[q][1][r];
                    }
            }
        }
        __syncthreads();

        // ---------------- P1 epilogue (role 0): LSTM c,h + export gh_r ------
        if (role == 0) {
            float s0 = 0.f, s1 = 0.f, s2 = 0.f, s3 = 0.f, s4 = 0.f;
#pragma unroll
            for (int wv = 0; wv < 8; ++wv) {
                s0 += lsum[0][wv][bq][cell];
                s1 += lsum[1][wv][bq][cell];
                s2 += lsum[2][wv][bq][cell];
                s3 += lsum[3][wv][bq][cell];
                s4 += lsum[4][wv][bq][cell];
            }
            const float* xwb = xw + ((size_t)t * BB + bq) * 4 * HH + kk0 + cell;
            float c = sigmf(s1 + xwb[HH]) * st_m + sigmf(s0 + xwb[0]) * tanhf_fast(s2 + xwb[2 * HH]);
            float h = sigmf(s3 + xwb[3 * HH]) * tanhf_fast(c);
            st_m = c;
            cbf[gidx]  = f2bf(c);
            hout[gidx] = f2bf(h);
            gh0_g[strip * 512 + tid] = s4 + b0;        // gh_r + bhh_r
        }
        grid_sync(bar, ++nbar * NBLK);     // c, h, gh_r visible everywhere

        // ---------------- P2 (role 1): gi MFMAs + GRU epilogue ----------------
        if (role == 1) {
            {
                const unsigned short* Ac = cbf + (size_t)l15 * HH + koff;
                f32x4 acc[3][2];
#pragma unroll
                for (int q = 0; q < 3; ++q) {
                    acc[q][0] = (f32x4){0.f, 0.f, 0.f, 0.f};
                    acc[q][1] = (f32x4){0.f, 0.f, 0.f, 0.f};
                }
#pragma unroll
                for (int it = 0; it < 8; ++it) {
                    s16x8 ac0 = *(const s16x8*)(Ac + it * 32);
                    s16x8 ac1 = *(const s16x8*)(Ac + 16 * HH + it * 32);
                    acc[0][0] = __builtin_amdgcn_mfma_f32_16x16x32_bf16(ac0, w5[2][it], acc[0][0], 0, 0, 0);
                    acc[0][1] = __builtin_amdgcn_mfma_f32_16x16x32_bf16(ac1, w5[2][it], acc[0][1], 0, 0, 0);
                    acc[1][0] = __builtin_amdgcn_mfma_f32_16x16x32_bf16(ac0, w5[3][it], acc[1][0], 0, 0, 0);
                    acc[1][1] = __builtin_amdgcn_mfma_f32_16x16x32_bf16(ac1, w5[3][it], acc[1][1], 0, 0, 0);
                    acc[2][0] = __builtin_amdgcn_mfma_f32_16x16x32_bf16(ac0, w5[4][it], acc[2][0], 0, 0, 0);
                    acc[2][1] = __builtin_amdgcn_mfma_f32_16x16x32_bf16(ac1, w5[4][it], acc[2][1], 0, 0, 0);
                }
#pragma unroll
                for (int q = 0; q < 3; ++q)
#pragma unroll
                    for (int r = 0; r < 4; ++r) {
                        lsum[2 + q][w][lq * 4 + r][l15]      = acc[q][0][r];
                        lsum[2 + q][w][16 + lq * 4 + r][l15] = acc[q][1][r];
                    }
            }
            __syncthreads();
            {
                float gz = 0.f, gn = 0.f, i0 = 0.f, i1 = 0.f, i2 = 0.f;
#pragma unroll
                for (int wv = 0; wv < 8; ++wv) {
                    gz += lsum[0][wv][bq][cell];   // gh_z (from P1, preserved)
                    gn += lsum[1][wv][bq][cell];   // gh_n (from P1, preserved)
                    i0 += lsum[2][wv][bq][cell];   // gi_r
                    i1 += lsum[3][wv][bq][cell];   // gi_z
                    i2 += lsum[4][wv][bq][cell];   // gi_n
                }
                float gr = gh0_g[strip * 512 + tid];          // gh_r + bhh_r
                float r = sigmf(i0 + b0 + gr);
                float z = sigmf(i1 + b1 + gz);
                float n = tanhf_fast(i2 + b2 + r * (gn + b3));
                float hg = (1.f - z) * n + z * st_m;
                st_m = hg;
                unsigned short hb = f2bf(hg);
                hgbf[gidx] = hb;
                hg_all[(size_t)t * BB * HH + gidx] = hb;
            }
        }
        if (t < TS - 1)
            grid_sync(bar, ++nbar * NBLK); // h, hg visible for next step
    }
}

// ---------------------------------------------------------------------------
// Phase C: out = hg_all @ linW.T + b. bf16 MFMA, 128x128 tile, BK=32.
// ---------------------------------------------------------------------------
__global__ __launch_bounds__(256) void out_gemm_kernel(
    const unsigned short* __restrict__ A,     // [1280][2048] (rows >=1248 junk)
    const unsigned short* __restrict__ Wl,    // [8000][2048] (reads to 8063 ok)
    const float* __restrict__ bl,
    float* __restrict__ out) {
    __shared__ unsigned short As[128][32];
    __shared__ unsigned short Bs[128][32];
    const int tid = threadIdx.x;
    const int lane = tid & 63;
    const int w = tid >> 6;
    const int l15 = lane & 15;
    const int lq = lane >> 4;
    const int mt = blockIdx.x, nt = blockIdx.y;
    const int mq = w >> 1, nq = w & 1;

    const int row0 = tid >> 2, kc0 = (tid & 3) * 8;
    const unsigned short* Ap0 = A + (size_t)(mt * 128 + row0) * HH + kc0;
    const unsigned short* Ap1 = A + (size_t)(mt * 128 + 64 + row0) * HH + kc0;
    const unsigned short* Bp0 = Wl + (size_t)(nt * 128 + row0) * HH + kc0;
    const unsigned short* Bp1 = Wl + (size_t)(nt * 128 + 64 + row0) * HH + kc0;

    f32x4 acc[4][4];
#pragma unroll
    for (int i = 0; i < 4; ++i)
#pragma unroll
        for (int j = 0; j < 4; ++j) acc[i][j] = (f32x4){0.f, 0.f, 0.f, 0.f};

    for (int k0 = 0; k0 < HH; k0 += 32) {
        s16x8 a0v = *(const s16x8*)(Ap0 + k0);
        s16x8 a1v = *(const s16x8*)(Ap1 + k0);
        s16x8 b0v = *(const s16x8*)(Bp0 + k0);
        s16x8 b1v = *(const s16x8*)(Bp1 + k0);
        *(s16x8*)&As[row0][kc0]      = a0v;
        *(s16x8*)&As[64 + row0][kc0] = a1v;
        *(s16x8*)&Bs[row0][kc0]      = b0v;
        *(s16x8*)&Bs[64 + row0][kc0] = b1v;
        __syncthreads();
        s16x8 af[4], bf[4];
#pragma unroll
        for (int i = 0; i < 4; ++i) af[i] = *(const s16x8*)&As[mq * 64 + i * 16 + l15][lq * 8];
#pragma unroll
        for (int j = 0; j < 4; ++j) bf[j] = *(const s16x8*)&Bs[nq * 64 + j * 16 + l15][lq * 8];
#pragma unroll
        for (int i = 0; i < 4; ++i)
#pragma unroll
            for (int j = 0; j < 4; ++j)
                acc[i][j] = __builtin_amdgcn_mfma_f32_16x16x32_bf16(af[i], bf[j], acc[i][j], 0, 0, 0);
        __syncthreads();
    }
#pragma unroll
    for (int j = 0; j < 4; ++j) {
        int n = nt * 128 + nq * 64 + j * 16 + l15;
        float bn = bl[n < VV ? n : VV - 1];
#pragma unroll
        for (int i = 0; i < 4; ++i) {
#pragma unroll
            for (int r = 0; r < 4; ++r) {
                int m = mt * 128 + mq * 64 + i * 16 + lq * 4 + r;
                if (m < TS * BB && n < VV) {
                    int t = m >> 5, b = m & 31;
                    out[((size_t)b * TS + t) * VV + n] = acc[i][j][r] + bn;
                }
            }
        }
    }
}

// ---------------------------------------------------------------------------
extern "C" void kernel_launch(void* const* d_in, const int* in_sizes, int n_in,
                              void* d_out, int out_size, void* d_ws, size_t ws_size,
                              hipStream_t stream) {
    const float* features = (const float*)d_in[0];
    const int*   captions = (const int*)d_in[1];
    const float* emb      = (const float*)d_in[2];
    const float* lstm_Wih = (const float*)d_in[3];
    const float* lstm_bih = (const float*)d_in[4];
    const float* lstm_Whh = (const float*)d_in[5];
    const float* lstm_bhh = (const float*)d_in[6];
    const float* gru_Wih  = (const float*)d_in[7];
    const float* gru_bih  = (const float*)d_in[8];
    const float* gru_Whh  = (const float*)d_in[9];
    const float* gru_bhh  = (const float*)d_in[10];
    const float* lin_W    = (const float*)d_in[11];
    const float* lin_b    = (const float*)d_in[12];
    float* out = (float*)d_out;

    // workspace layout
    unsigned short* us = (unsigned short*)d_ws;
    unsigned short* linW_bf = us;                              // 8000*2048
    unsigned short* hbf0    = linW_bf + (size_t)VV * HH;       // (out_gemm may
    unsigned short* hbf1    = hbf0 + BB * HH;                  //  over-read into
    unsigned short* cbf     = hbf1 + BB * HH;                  //  these - benign)
    unsigned short* hgbf    = cbf  + BB * HH;
    unsigned short* hg_all  = hgbf + BB * HH;                  // 1280*2048 (padded)
    float* xw = (float*)(hg_all + (size_t)1280 * HH);          // 39*32*8192
    float* gh0_g = xw + (size_t)TS * BB * 4 * HH;              // 128*512
    unsigned int* bar = (unsigned int*)(gh0_g + 128 * 512);

    // 1) bf16 convert for the output GEMM weight only
    convert_kernel<<<(VV * HH / 4 + 255) / 256, 256, 0, stream>>>(lin_W, linW_bf, VV * HH / 4);

    // 2) precompute x-side gate biases for all steps
    embed_proj_kernel<<<dim3(4 * HH / 256, TS), 256, 0, stream>>>(
        captions, emb, lstm_Wih, lstm_bih, lstm_bhh, xw);

    // 3) init bf16 states + zero grid barrier
    init_state_kernel<<<(BB * HH) / 256, 256, 0, stream>>>(features, hbf0, hgbf, bar);

    // 4) persistent recurrence: 5 weight tiles/block register-resident
    recurrence_kernel<<<NBLK, 512, 0, stream>>>(
        lstm_Whh, gru_Whh, gru_Wih, gru_bhh, gru_bih, features, xw,
        hbf0, hbf1, hgbf, cbf, gh0_g, hg_all, bar);

    // 5) output projection
    out_gemm_kernel<<<dim3((TS * BB + 127) / 128, (VV + 127) / 128), 256, 0, stream>>>(
        hg_all, linW_bf, lin_b, out);
}

// Round 4
// 2752.534 us; speedup vs baseline: 1.3988x; 1.0417x over previous
//
#include <hip/hip_runtime.h>

#define BB 32
#define TT 40
#define TS 39
#define VV 8000
#define EE 50
#define HH 2048
#define NBLK 256

typedef short s16x8 __attribute__((ext_vector_type(8)));
typedef float f32x4 __attribute__((ext_vector_type(4)));

__device__ __forceinline__ float sigmf(float x) { return 1.0f / (1.0f + __expf(-x)); }
__device__ __forceinline__ float tanhf_fast(float x) { return 2.0f / (1.0f + __expf(-2.0f * x)) - 1.0f; }

__device__ __forceinline__ unsigned short f2bf(float x) {
    union { float f; unsigned u; } v; v.f = x;
    unsigned r = v.u + 0x7FFF + ((v.u >> 16) & 1);   // RNE
    return (unsigned short)(r >> 16);
}

// 8 consecutive fp32 -> s16x8 bf16 fragment (32B-aligned source)
__device__ __forceinline__ s16x8 cvt8(const float* p) {
    float4 a = *(const float4*)p;
    float4 b = *(const float4*)(p + 4);
    s16x8 r;
    r[0] = (short)f2bf(a.x); r[1] = (short)f2bf(a.y);
    r[2] = (short)f2bf(a.z); r[3] = (short)f2bf(a.w);
    r[4] = (short)f2bf(b.x); r[5] = (short)f2bf(b.y);
    r[6] = (short)f2bf(b.z); r[7] = (short)f2bf(b.w);
    return r;
}

// ---------------------------------------------------------------------------
// fp32 -> bf16 conversion (lin_W only), 4 elems/thread
// ---------------------------------------------------------------------------
__global__ void convert_kernel(const float* __restrict__ src,
                               unsigned short* __restrict__ dst, int n4) {
    int i = blockIdx.x * 256 + threadIdx.x;
    if (i < n4) {
        float4 v = ((const float4*)src)[i];
        ushort4 o;
        o.x = f2bf(v.x); o.y = f2bf(v.y); o.z = f2bf(v.z); o.w = f2bf(v.w);
        ((ushort4*)dst)[i] = o;
    }
}

// ---------------------------------------------------------------------------
// Phase A: xw[t][b][j] = emb[captions[b][t]] . Wih[j][:] + bih[j] + bhh[j]
// ---------------------------------------------------------------------------
__global__ void embed_proj_kernel(const int* __restrict__ caps,
                                  const float* __restrict__ emb,
                                  const float* __restrict__ Wih,
                                  const float* __restrict__ bih,
                                  const float* __restrict__ bhh,
                                  float* __restrict__ xw) {
    __shared__ float elds[BB][EE];
    int t = blockIdx.y;
    int j = blockIdx.x * 256 + threadIdx.x;
    for (int idx = threadIdx.x; idx < BB * EE; idx += 256) {
        int bl = idx / EE, e = idx - bl * EE;
        elds[bl][e] = emb[(size_t)caps[bl * TT + t] * EE + e];
    }
    __syncthreads();
    float wreg[EE];
#pragma unroll
    for (int e = 0; e < EE; ++e) wreg[e] = Wih[(size_t)j * EE + e];
    float bias = bih[j] + bhh[j];
    for (int bl = 0; bl < BB; ++bl) {
        float acc = bias;
#pragma unroll
        for (int e = 0; e < EE; ++e) acc += wreg[e] * elds[bl][e];
        xw[((size_t)(t * BB + bl)) * (4 * HH) + j] = acc;
    }
}

// ---------------------------------------------------------------------------
// Init: bf16 state copies (h, hg) + zero the barrier flags/go (d_ws poisoned).
// ---------------------------------------------------------------------------
__global__ void init_state_kernel(const float* __restrict__ feat,
                                  unsigned short* __restrict__ hbf,
                                  unsigned short* __restrict__ hgbf,
                                  unsigned int* __restrict__ flags) {
    int i = blockIdx.x * 256 + threadIdx.x;    // 65536 threads
    unsigned short b = f2bf(feat[i]);
    hbf[i] = b; hgbf[i] = b;
    if (i < NBLK * 16 + 16) flags[i] = 0u;     // flags[256*16] + go
}

// ---------------------------------------------------------------------------
// Grid barrier with ZERO same-line RMWs (round-3 counter barrier serialized
// 256 same-cacheline atomic adds ~ 32 us/phase).
//  - block b (b>0): release-STORE epoch to its own 64B-spaced flag, then
//    relaxed-poll `go` (same-line LOADS pipeline fine; relaxed agent polling
//    is HW-verified by rounds 1-3 passing).
//  - master (block 0): threads 1..255 each spin on one flag; then thread 0
//    release-stores go = epoch.
// Release store = wbl2 writeback before store (data visible); ACQUIRE fence
// on exit invalidates L1/L2 once per block (G16 discipline).
// ---------------------------------------------------------------------------
__device__ __forceinline__ void grid_sync(unsigned int* flags, unsigned int* go,
                                          unsigned int epoch) {
    __syncthreads();
    if (blockIdx.x == 0) {
        if (threadIdx.x > 0 && threadIdx.x < NBLK) {
            while (__hip_atomic_load(&flags[threadIdx.x * 16], __ATOMIC_RELAXED,
                                     __HIP_MEMORY_SCOPE_AGENT) < epoch)
                __builtin_amdgcn_s_sleep(1);
        }
        __syncthreads();
        if (threadIdx.x == 0)
            __hip_atomic_store(go, epoch, __ATOMIC_RELEASE, __HIP_MEMORY_SCOPE_AGENT);
    } else {
        if (threadIdx.x == 0) {
            __hip_atomic_store(&flags[blockIdx.x * 16], epoch, __ATOMIC_RELEASE,
                               __HIP_MEMORY_SCOPE_AGENT);
            while (__hip_atomic_load(go, __ATOMIC_RELAXED,
                                     __HIP_MEMORY_SCOPE_AGENT) < epoch)
                __builtin_amdgcn_s_sleep(1);
        }
        __syncthreads();
    }
    __builtin_amdgcn_fence(__ATOMIC_ACQUIRE, "agent");
}

// ---------------------------------------------------------------------------
// Persistent recurrence, weights register-resident for all 39 steps.
// (Structure identical to round 3 — single-variable change is the barrier.)
// 256 blocks = 128 strips x 2 roles; 512 threads (8 waves); 1 block/CU.
// Wave w owns K-slice [w*256, w*256+256) -> 8 ksteps of 32.
// Each wave holds FIVE weight tiles x 8 ksteps = 40 s16x8 = 160 VGPRs:
//   role 0: LSTM {i,f,g,o} + GRU gh_r      (P1: 5 tiles x 2 batch halves)
//   role 1: GRU {gh_z, gh_n} (P1) + gi {r,z,n} (P2, A = c_t)
// Cross-wave K-reduction via LDS lsum; role-1's gh_z/gh_n sums persist in
// lsum[0..1] across the mid barrier (P2 writes only lsum[2..4]).
// gh_r (+bias) crosses roles via gh0_g global buffer at the mid barrier.
// c (role 0) and hg (role 1) fp32 masters live in epilogue-thread registers.
// ---------------------------------------------------------------------------
__global__ __launch_bounds__(512, 2) void recurrence_kernel(
    const float* __restrict__ Whh,     // [8192][2048] fp32
    const float* __restrict__ gWhh,    // [6144][2048] fp32
    const float* __restrict__ gWih,    // [6144][2048] fp32
    const float* __restrict__ gbhh,    // [6144]
    const float* __restrict__ gbih,    // [6144]
    const float* __restrict__ feat,    // [32][2048]
    const float* __restrict__ xw,      // [39][32][8192]
    unsigned short* __restrict__ hbf0, // [32][2048] ping
    unsigned short* __restrict__ hbf1, // [32][2048] pong
    unsigned short* __restrict__ hgbf, // [32][2048]
    unsigned short* __restrict__ cbf,  // [32][2048]
    float* __restrict__ gh0_g,         // [128][512] gh_r + bias, role0 -> role1
    unsigned short* __restrict__ hg_all, // [39*32][2048]
    unsigned int* flags, unsigned int* go)
{
    __shared__ float lsum[5][8][32][17];   // [tile][wave][m=batch][n=cell] 87KB

    const int tid = threadIdx.x;
    const int lane = tid & 63;
    const int w = tid >> 6;          // 0..7
    const int l15 = lane & 15;
    const int lq = lane >> 4;        // 0..3
    const int bx = blockIdx.x;
    const int role = bx & 1;
    const int strip = bx >> 1;
    const int kk0 = strip * 16;
    const int koff = w * 256 + lq * 8;

    // ---- one-time: 5 weight tiles -> registers (fp32 read, bf16 in-reg) ----
    const size_t rstep = (size_t)HH * HH;
    const size_t rowoff = (size_t)(kk0 + l15) * HH + koff;
    const float* wrow[5];
    if (role == 0) {
        wrow[0] = Whh + rowoff;                 // LSTM i
        wrow[1] = Whh + rstep + rowoff;         // LSTM f
        wrow[2] = Whh + 2 * rstep + rowoff;     // LSTM g
        wrow[3] = Whh + 3 * rstep + rowoff;     // LSTM o
        wrow[4] = gWhh + rowoff;                // GRU gh_r
    } else {
        wrow[0] = gWhh + rstep + rowoff;        // GRU gh_z
        wrow[1] = gWhh + 2 * rstep + rowoff;    // GRU gh_n
        wrow[2] = gWih + rowoff;                // GRU gi_r
        wrow[3] = gWih + rstep + rowoff;        // GRU gi_z
        wrow[4] = gWih + 2 * rstep + rowoff;    // GRU gi_n
    }
    s16x8 w5[5][8];
#pragma unroll
    for (int q = 0; q < 5; ++q)
#pragma unroll
        for (int it = 0; it < 8; ++it)
            w5[q][it] = cvt8(wrow[q] + it * 32);

    // ---- per-element master state + biases (all 512 threads: 32b x 16cell) ----
    const int cell = tid & 15;
    const int bq = tid >> 4;                 // 0..31
    const int gidx = bq * HH + kk0 + cell;
    float st_m;                              // role0: c master, role1: hg master
    float b0 = 0.f, b1 = 0.f, b2 = 0.f, b3 = 0.f;
    {
        st_m = feat[gidx];
        if (role == 0) {
            b0 = gbhh[kk0 + cell];                    // bhh_r (goes with gh_r)
        } else {
            b0 = gbih[kk0 + cell];                    // bih_r
            b1 = gbih[HH + kk0 + cell] + gbhh[HH + kk0 + cell];      // z biases
            b2 = gbih[2 * HH + kk0 + cell];           // bih_n
            b3 = gbhh[2 * HH + kk0 + cell];           // bhh_n (inside r*)
        }
    }

    unsigned int nbar = 0;
    for (int t = 0; t < TS; ++t) {
        const unsigned short* hin  = (t & 1) ? hbf1 : hbf0;
        unsigned short*       hout = (t & 1) ? hbf0 : hbf1;

        // ---------------- P1 MFMAs ----------------
        {
            f32x4 acc[5][2];
#pragma unroll
            for (int q = 0; q < 5; ++q) {
                acc[q][0] = (f32x4){0.f, 0.f, 0.f, 0.f};
                acc[q][1] = (f32x4){0.f, 0.f, 0.f, 0.f};
            }
            if (role == 0) {
                const unsigned short* Ah = hin  + (size_t)l15 * HH + koff;
                const unsigned short* Ag = hgbf + (size_t)l15 * HH + koff;
#pragma unroll
                for (int it = 0; it < 8; ++it) {
                    s16x8 ah0 = *(const s16x8*)(Ah + it * 32);
                    s16x8 ah1 = *(const s16x8*)(Ah + 16 * HH + it * 32);
                    s16x8 ag0 = *(const s16x8*)(Ag + it * 32);
                    s16x8 ag1 = *(const s16x8*)(Ag + 16 * HH + it * 32);
                    acc[0][0] = __builtin_amdgcn_mfma_f32_16x16x32_bf16(ah0, w5[0][it], acc[0][0], 0, 0, 0);
                    acc[0][1] = __builtin_amdgcn_mfma_f32_16x16x32_bf16(ah1, w5[0][it], acc[0][1], 0, 0, 0);
                    acc[1][0] = __builtin_amdgcn_mfma_f32_16x16x32_bf16(ah0, w5[1][it], acc[1][0], 0, 0, 0);
                    acc[1][1] = __builtin_amdgcn_mfma_f32_16x16x32_bf16(ah1, w5[1][it], acc[1][1], 0, 0, 0);
                    acc[2][0] = __builtin_amdgcn_mfma_f32_16x16x32_bf16(ah0, w5[2][it], acc[2][0], 0, 0, 0);
                    acc[2][1] = __builtin_amdgcn_mfma_f32_16x16x32_bf16(ah1, w5[2][it], acc[2][1], 0, 0, 0);
                    acc[3][0] = __builtin_amdgcn_mfma_f32_16x16x32_bf16(ah0, w5[3][it], acc[3][0], 0, 0, 0);
                    acc[3][1] = __builtin_amdgcn_mfma_f32_16x16x32_bf16(ah1, w5[3][it], acc[3][1], 0, 0, 0);
                    acc[4][0] = __builtin_amdgcn_mfma_f32_16x16x32_bf16(ag0, w5[4][it], acc[4][0], 0, 0, 0);
                    acc[4][1] = __builtin_amdgcn_mfma_f32_16x16x32_bf16(ag1, w5[4][it], acc[4][1], 0, 0, 0);
                }
#pragma unroll
                for (int q = 0; q < 5; ++q)
#pragma unroll
                    for (int r = 0; r < 4; ++r) {
                        lsum[q][w][lq * 4 + r][l15]      = acc[q][0][r];
                        lsum[q][w][16 + lq * 4 + r][l15] = acc[q][1][r];
                    }
            } else {
                const unsigned short* Ag = hgbf + (size_t)l15 * HH + koff;
#pragma unroll
                for (int it = 0; it < 8; ++it) {
                    s16x8 ag0 = *(const s16x8*)(Ag + it * 32);
                    s16x8 ag1 = *(const s16x8*)(Ag + 16 * HH + it * 32);
                    acc[0][0] = __builtin_amdgcn_mfma_f32_16x16x32_bf16(ag0, w5[0][it], acc[0][0], 0, 0, 0);
                    acc[0][1] = __builtin_amdgcn_mfma_f32_16x16x32_bf16(ag1, w5[0][it], acc[0][1], 0, 0, 0);
                    acc[1][0] = __builtin_amdgcn_mfma_f32_16x16x32_bf16(ag0, w5[1][it], acc[1][0], 0, 0, 0);
                    acc[1][1] = __builtin_amdgcn_mfma_f32_16x16x32_bf16(ag1, w5[1][it], acc[1][1], 0, 0, 0);
                }
#pragma unroll
                for (int q = 0; q < 2; ++q)
#pragma unroll
                    for (int r = 0; r < 4; ++r) {
                        lsum[q][w][lq * 4 + r][l15]      = acc[q][0][r];
                        lsum[q][w][16 + lq * 4 + r][l15] = acc[q][1][r];
                    }
            }
        }
        __syncthreads();

        // ---------------- P1 epilogue (role 0): LSTM c,h + export gh_r ------
        if (role == 0) {
            float s0 = 0.f, s1 = 0.f, s2 = 0.f, s3 = 0.f, s4 = 0.f;
#pragma unroll
            for (int wv = 0; wv < 8; ++wv) {
                s0 += lsum[0][wv][bq][cell];
                s1 += lsum[1][wv][bq][cell];
                s2 += lsum[2][wv][bq][cell];
                s3 += lsum[3][wv][bq][cell];
                s4 += lsum[4][wv][bq][cell];
            }
            const float* xwb = xw + ((size_t)t * BB + bq) * 4 * HH + kk0 + cell;
            float c = sigmf(s1 + xwb[HH]) * st_m + sigmf(s0 + xwb[0]) * tanhf_fast(s2 + xwb[2 * HH]);
            float h = sigmf(s3 + xwb[3 * HH]) * tanhf_fast(c);
            st_m = c;
            cbf[gidx]  = f2bf(c);
            hout[gidx] = f2bf(h);
            gh0_g[strip * 512 + tid] = s4 + b0;        // gh_r + bhh_r
        }
        grid_sync(flags, go, ++nbar);      // c, h, gh_r visible everywhere

        // ---------------- P2 (role 1): gi MFMAs + GRU epilogue ----------------
        if (role == 1) {
            {
                const unsigned short* Ac = cbf + (size_t)l15 * HH + koff;
                f32x4 acc[3][2];
#pragma unroll
                for (int q = 0; q < 3; ++q) {
                    acc[q][0] = (f32x4){0.f, 0.f, 0.f, 0.f};
                    acc[q][1] = (f32x4){0.f, 0.f, 0.f, 0.f};
                }
#pragma unroll
                for (int it = 0; it < 8; ++it) {
                    s16x8 ac0 = *(const s16x8*)(Ac + it * 32);
                    s16x8 ac1 = *(const s16x8*)(Ac + 16 * HH + it * 32);
                    acc[0][0] = __builtin_amdgcn_mfma_f32_16x16x32_bf16(ac0, w5[2][it], acc[0][0], 0, 0, 0);
                    acc[0][1] = __builtin_amdgcn_mfma_f32_16x16x32_bf16(ac1, w5[2][it], acc[0][1], 0, 0, 0);
                    acc[1][0] = __builtin_amdgcn_mfma_f32_16x16x32_bf16(ac0, w5[3][it], acc[1][0], 0, 0, 0);
                    acc[1][1] = __builtin_amdgcn_mfma_f32_16x16x32_bf16(ac1, w5[3][it], acc[1][1], 0, 0, 0);
                    acc[2][0] = __builtin_amdgcn_mfma_f32_16x16x32_bf16(ac0, w5[4][it], acc[2][0], 0, 0, 0);
                    acc[2][1] = __builtin_amdgcn_mfma_f32_16x16x32_bf16(ac1, w5[4][it], acc[2][1], 0, 0, 0);
                }
#pragma unroll
                for (int q = 0; q < 3; ++q)
#pragma unroll
                    for (int r = 0; r < 4; ++r) {
                        lsum[2 + q][w][lq * 4 + r][l15]      = acc[q][0][r];
                        lsum[2 + q][w][16 + lq * 4 + r][l15] = acc[q][1][r];
                    }
            }
            __syncthreads();
            {
                float gz = 0.f, gn = 0.f, i0 = 0.f, i1 = 0.f, i2 = 0.f;
#pragma unroll
                for (int wv = 0; wv < 8; ++wv) {
                    gz += lsum[0][wv][bq][cell];   // gh_z (from P1, preserved)
                    gn += lsum[1][wv][bq][cell];   // gh_n (from P1, preserved)
                    i0 += lsum[2][wv][bq][cell];   // gi_r
                    i1 += lsum[3][wv][bq][cell];   // gi_z
                    i2 += lsum[4][wv][bq][cell];   // gi_n
                }
                float gr = gh0_g[strip * 512 + tid];          // gh_r + bhh_r
                float r = sigmf(i0 + b0 + gr);
                float z = sigmf(i1 + b1 + gz);
                float n = tanhf_fast(i2 + b2 + r * (gn + b3));
                float hg = (1.f - z) * n + z * st_m;
                st_m = hg;
                unsigned short hb = f2bf(hg);
                hgbf[gidx] = hb;
                hg_all[(size_t)t * BB * HH + gidx] = hb;
            }
        }
        if (t < TS - 1)
            grid_sync(flags, go, ++nbar);  // h, hg visible for next step
    }
}

// ---------------------------------------------------------------------------
// Phase C: out = hg_all @ linW.T + b. bf16 MFMA, 128x128 tile, BK=32.
// ---------------------------------------------------------------------------
__global__ __launch_bounds__(256) void out_gemm_kernel(
    const unsigned short* __restrict__ A,     // [1280][2048] (rows >=1248 junk)
    const unsigned short* __restrict__ Wl,    // [8000][2048] (reads to 8063 ok)
    const float* __restrict__ bl,
    float* __restrict__ out) {
    __shared__ unsigned short As[128][32];
    __shared__ unsigned short Bs[128][32];
    const int tid = threadIdx.x;
    const int lane = tid & 63;
    const int w = tid >> 6;
    const int l15 = lane & 15;
    const int lq = lane >> 4;
    const int mt = blockIdx.x, nt = blockIdx.y;
    const int mq = w >> 1, nq = w & 1;

    const int row0 = tid >> 2, kc0 = (tid & 3) * 8;
    const unsigned short* Ap0 = A + (size_t)(mt * 128 + row0) * HH + kc0;
    const unsigned short* Ap1 = A + (size_t)(mt * 128 + 64 + row0) * HH + kc0;
    const unsigned short* Bp0 = Wl + (size_t)(nt * 128 + row0) * HH + kc0;
    const unsigned short* Bp1 = Wl + (size_t)(nt * 128 + 64 + row0) * HH + kc0;

    f32x4 acc[4][4];
#pragma unroll
    for (int i = 0; i < 4; ++i)
#pragma unroll
        for (int j = 0; j < 4; ++j) acc[i][j] = (f32x4){0.f, 0.f, 0.f, 0.f};

    for (int k0 = 0; k0 < HH; k0 += 32) {
        s16x8 a0v = *(const s16x8*)(Ap0 + k0);
        s16x8 a1v = *(const s16x8*)(Ap1 + k0);
        s16x8 b0v = *(const s16x8*)(Bp0 + k0);
        s16x8 b1v = *(const s16x8*)(Bp1 + k0);
        *(s16x8*)&As[row0][kc0]      = a0v;
        *(s16x8*)&As[64 + row0][kc0] = a1v;
        *(s16x8*)&Bs[row0][kc0]      = b0v;
        *(s16x8*)&Bs[64 + row0][kc0] = b1v;
        __syncthreads();
        s16x8 af[4], bf[4];
#pragma unroll
        for (int i = 0; i < 4; ++i) af[i] = *(const s16x8*)&As[mq * 64 + i * 16 + l15][lq * 8];
#pragma unroll
        for (int j = 0; j < 4; ++j) bf[j] = *(const s16x8*)&Bs[nq * 64 + j * 16 + l15][lq * 8];
#pragma unroll
        for (int i = 0; i < 4; ++i)
#pragma unroll
            for (int j = 0; j < 4; ++j)
                acc[i][j] = __builtin_amdgcn_mfma_f32_16x16x32_bf16(af[i], bf[j], acc[i][j], 0, 0, 0);
        __syncthreads();
    }
#pragma unroll
    for (int j = 0; j < 4; ++j) {
        int n = nt * 128 + nq * 64 + j * 16 + l15;
        float bn = bl[n < VV ? n : VV - 1];
#pragma unroll
        for (int i = 0; i < 4; ++i) {
#pragma unroll
            for (int r = 0; r < 4; ++r) {
                int m = mt * 128 + mq * 64 + i * 16 + lq * 4 + r;
                if (m < TS * BB && n < VV) {
                    int t = m >> 5, b = m & 31;
                    out[((size_t)b * TS + t) * VV + n] = acc[i][j][r] + bn;
                }
            }
        }
    }
}

// ---------------------------------------------------------------------------
extern "C" void kernel_launch(void* const* d_in, const int* in_sizes, int n_in,
                              void* d_out, int out_size, void* d_ws, size_t ws_size,
                              hipStream_t stream) {
    const float* features = (const float*)d_in[0];
    const int*   captions = (const int*)d_in[1];
    const float* emb      = (const float*)d_in[2];
    const float* lstm_Wih = (const float*)d_in[3];
    const float* lstm_bih = (const float*)d_in[4];
    const float* lstm_Whh = (const float*)d_in[5];
    const float* lstm_bhh = (const float*)d_in[6];
    const float* gru_Wih  = (const float*)d_in[7];
    const float* gru_bih  = (const float*)d_in[8];
    const float* gru_Whh  = (const float*)d_in[9];
    const float* gru_bhh  = (const float*)d_in[10];
    const float* lin_W    = (const float*)d_in[11];
    const float* lin_b    = (const float*)d_in[12];
    float* out = (float*)d_out;

    // workspace layout
    unsigned short* us = (unsigned short*)d_ws;
    unsigned short* linW_bf = us;                              // 8000*2048
    unsigned short* hbf0    = linW_bf + (size_t)VV * HH;       // (out_gemm may
    unsigned short* hbf1    = hbf0 + BB * HH;                  //  over-read into
    unsigned short* cbf     = hbf1 + BB * HH;                  //  these - benign)
    unsigned short* hgbf    = cbf  + BB * HH;
    unsigned short* hg_all  = hgbf + BB * HH;                  // 1280*2048 (padded)
    float* xw = (float*)(hg_all + (size_t)1280 * HH);          // 39*32*8192
    float* gh0_g = xw + (size_t)TS * BB * 4 * HH;              // 128*512
    unsigned int* flags = (unsigned int*)(gh0_g + 128 * 512);  // 256*16 + go
    unsigned int* go = flags + NBLK * 16;

    // 1) bf16 convert for the output GEMM weight only
    convert_kernel<<<(VV * HH / 4 + 255) / 256, 256, 0, stream>>>(lin_W, linW_bf, VV * HH / 4);

    // 2) precompute x-side gate biases for all steps
    embed_proj_kernel<<<dim3(4 * HH / 256, TS), 256, 0, stream>>>(
        captions, emb, lstm_Wih, lstm_bih, lstm_bhh, xw);

    // 3) init bf16 states + zero barrier flags
    init_state_kernel<<<(BB * HH) / 256, 256, 0, stream>>>(features, hbf0, hgbf, flags);

    // 4) persistent recurrence: 5 weight tiles/block register-resident
    recurrence_kernel<<<NBLK, 512, 0, stream>>>(
        lstm_Whh, gru_Whh, gru_Wih, gru_bhh, gru_bih, features, xw,
        hbf0, hbf1, hgbf, cbf, gh0_g, hg_all, flags, go);

    // 5) output projection
    out_gemm_kernel<<<dim3((TS * BB + 127) / 128, (VV + 127) / 128), 256, 0, stream>>>(
        hg_all, linW_bf, lin_b, out);
}

// Round 5
// 1721.986 us; speedup vs baseline: 2.2359x; 1.5985x over previous
//
#include <hip/hip_runtime.h>

#define BB 32
#define TT 40
#define TS 39
#define VV 8000
#define EE 50
#define HH 2048
#define NBLK 256

typedef short s16x8 __attribute__((ext_vector_type(8)));
typedef float f32x4 __attribute__((ext_vector_type(4)));

__device__ __forceinline__ float sigmf(float x) { return 1.0f / (1.0f + __expf(-x)); }
__device__ __forceinline__ float tanhf_fast(float x) { return 2.0f / (1.0f + __expf(-2.0f * x)) - 1.0f; }

__device__ __forceinline__ unsigned short f2bf(float x) {
    union { float f; unsigned u; } v; v.f = x;
    unsigned r = v.u + 0x7FFF + ((v.u >> 16) & 1);   // RNE
    return (unsigned short)(r >> 16);
}

// 8 consecutive fp32 -> s16x8 bf16 fragment (32B-aligned source)
__device__ __forceinline__ s16x8 cvt8(const float* p) {
    float4 a = *(const float4*)p;
    float4 b = *(const float4*)(p + 4);
    s16x8 r;
    r[0] = (short)f2bf(a.x); r[1] = (short)f2bf(a.y);
    r[2] = (short)f2bf(a.z); r[3] = (short)f2bf(a.w);
    r[4] = (short)f2bf(b.x); r[5] = (short)f2bf(b.y);
    r[6] = (short)f2bf(b.z); r[7] = (short)f2bf(b.w);
    return r;
}

// Coherent (agent-scope, cache-bypassing) 16B bf16-fragment load: two relaxed
// u64 atomic loads -> global_load_dwordx2 sc0 sc1 served at the MALL coherence
// point. No fences needed anywhere; never invalidates L1/L2.
__device__ __forceinline__ s16x8 cohload16(const unsigned short* p) {
    union { unsigned long long u[2]; s16x8 v; } r;
    const unsigned long long* q = (const unsigned long long*)p;
    r.u[0] = __hip_atomic_load(q,     __ATOMIC_RELAXED, __HIP_MEMORY_SCOPE_AGENT);
    r.u[1] = __hip_atomic_load(q + 1, __ATOMIC_RELAXED, __HIP_MEMORY_SCOPE_AGENT);
    return r.v;
}

// ---------------------------------------------------------------------------
// fp32 -> bf16 conversion (lin_W only), 4 elems/thread
// ---------------------------------------------------------------------------
__global__ void convert_kernel(const float* __restrict__ src,
                               unsigned short* __restrict__ dst, int n4) {
    int i = blockIdx.x * 256 + threadIdx.x;
    if (i < n4) {
        float4 v = ((const float4*)src)[i];
        ushort4 o;
        o.x = f2bf(v.x); o.y = f2bf(v.y); o.z = f2bf(v.z); o.w = f2bf(v.w);
        ((ushort4*)dst)[i] = o;
    }
}

// ---------------------------------------------------------------------------
// Phase A: xw[t][b][j] = emb[captions[b][t]] . Wih[j][:] + bih[j] + bhh[j]
// ---------------------------------------------------------------------------
__global__ void embed_proj_kernel(const int* __restrict__ caps,
                                  const float* __restrict__ emb,
                                  const float* __restrict__ Wih,
                                  const float* __restrict__ bih,
                                  const float* __restrict__ bhh,
                                  float* __restrict__ xw) {
    __shared__ float elds[BB][EE];
    int t = blockIdx.y;
    int j = blockIdx.x * 256 + threadIdx.x;
    for (int idx = threadIdx.x; idx < BB * EE; idx += 256) {
        int bl = idx / EE, e = idx - bl * EE;
        elds[bl][e] = emb[(size_t)caps[bl * TT + t] * EE + e];
    }
    __syncthreads();
    float wreg[EE];
#pragma unroll
    for (int e = 0; e < EE; ++e) wreg[e] = Wih[(size_t)j * EE + e];
    float bias = bih[j] + bhh[j];
    for (int bl = 0; bl < BB; ++bl) {
        float acc = bias;
#pragma unroll
        for (int e = 0; e < EE; ++e) acc += wreg[e] * elds[bl][e];
        xw[((size_t)(t * BB + bl)) * (4 * HH) + j] = acc;
    }
}

// ---------------------------------------------------------------------------
// Init: bf16 state copies (h, hg) + zero the barrier flags/go (d_ws poisoned).
// ---------------------------------------------------------------------------
__global__ void init_state_kernel(const float* __restrict__ feat,
                                  unsigned short* __restrict__ hbf,
                                  unsigned short* __restrict__ hgbf,
                                  unsigned int* __restrict__ flags) {
    int i = blockIdx.x * 256 + threadIdx.x;    // 65536 threads
    unsigned short b = f2bf(feat[i]);
    hbf[i] = b; hgbf[i] = b;
    if (i < NBLK * 16 + 16) flags[i] = 0u;     // flags[256*16] + go
}

// ---------------------------------------------------------------------------
// Fence-free grid barrier. All data that crosses blocks is accessed via
// relaxed agent-scope atomics (coherent at MALL), so NO release/acquire cache
// maintenance is needed. Ordering: __syncthreads drains vmcnt(0) per wave
// (store-ack at the coherence point = visible) before the flag store.
//  - block b>0: relaxed-store epoch to own 64B-spaced flag, poll `go`.
//  - master: threads 1..255 spin on one flag each; then store go = epoch.
// Workgroup-scope acquire fence on exit = compiler ordering only (no HW op).
// ---------------------------------------------------------------------------
__device__ __forceinline__ void grid_sync(unsigned int* flags, unsigned int* go,
                                          unsigned int epoch) {
    __syncthreads();
    if (blockIdx.x == 0) {
        if (threadIdx.x > 0 && threadIdx.x < NBLK) {
            while (__hip_atomic_load(&flags[threadIdx.x * 16], __ATOMIC_RELAXED,
                                     __HIP_MEMORY_SCOPE_AGENT) < epoch)
                __builtin_amdgcn_s_sleep(1);
        }
        __syncthreads();
        if (threadIdx.x == 0)
            __hip_atomic_store(go, epoch, __ATOMIC_RELAXED, __HIP_MEMORY_SCOPE_AGENT);
    } else {
        if (threadIdx.x == 0) {
            __hip_atomic_store(&flags[blockIdx.x * 16], epoch, __ATOMIC_RELAXED,
                               __HIP_MEMORY_SCOPE_AGENT);
            while (__hip_atomic_load(go, __ATOMIC_RELAXED,
                                     __HIP_MEMORY_SCOPE_AGENT) < epoch)
                __builtin_amdgcn_s_sleep(1);
        }
        __syncthreads();
    }
    __builtin_amdgcn_fence(__ATOMIC_ACQUIRE, "workgroup");   // compiler ordering, ~free
}

// ---------------------------------------------------------------------------
// Persistent recurrence, weights register-resident for all 39 steps.
// (Structure identical to rounds 3-4 — single-variable change: explicit
//  MALL coherence for cross-block state instead of cache fences.)
// 256 blocks = 128 strips x 2 roles; 512 threads (8 waves); 1 block/CU.
// Wave w owns K-slice [w*256, w*256+256) -> 8 ksteps of 32.
// Each wave holds FIVE weight tiles x 8 ksteps = 40 s16x8 = 160 VGPRs:
//   role 0: LSTM {i,f,g,o} + GRU gh_r      (P1: 5 tiles x 2 batch halves)
//   role 1: GRU {gh_z, gh_n} (P1) + gi {r,z,n} (P2, A = c_t)
// Cross-block buffers (hbf0/1, hgbf, cbf, gh0_g): coherent atomic access.
// Private / read-only (weights, xw, biases, hg_all): normal cached access —
// L2 is never invalidated, so these stay hot across all 39 steps.
// ---------------------------------------------------------------------------
__global__ __launch_bounds__(512, 2) void recurrence_kernel(
    const float* __restrict__ Whh,     // [8192][2048] fp32
    const float* __restrict__ gWhh,    // [6144][2048] fp32
    const float* __restrict__ gWih,    // [6144][2048] fp32
    const float* __restrict__ gbhh,    // [6144]
    const float* __restrict__ gbih,    // [6144]
    const float* __restrict__ feat,    // [32][2048]
    const float* __restrict__ xw,      // [39][32][8192]
    unsigned short* __restrict__ hbf0, // [32][2048] ping
    unsigned short* __restrict__ hbf1, // [32][2048] pong
    unsigned short* __restrict__ hgbf, // [32][2048]
    unsigned short* __restrict__ cbf,  // [32][2048]
    float* __restrict__ gh0_g,         // [128][512] gh_r + bias, role0 -> role1
    unsigned short* __restrict__ hg_all, // [39*32][2048]
    unsigned int* flags, unsigned int* go)
{
    __shared__ float lsum[5][8][32][17];   // [tile][wave][m=batch][n=cell] 87KB

    const int tid = threadIdx.x;
    const int lane = tid & 63;
    const int w = tid >> 6;          // 0..7
    const int l15 = lane & 15;
    const int lq = lane >> 4;        // 0..3
    const int bx = blockIdx.x;
    const int role = bx & 1;
    const int strip = bx >> 1;
    const int kk0 = strip * 16;
    const int koff = w * 256 + lq * 8;

    // ---- one-time: 5 weight tiles -> registers (fp32 read, bf16 in-reg) ----
    const size_t rstep = (size_t)HH * HH;
    const size_t rowoff = (size_t)(kk0 + l15) * HH + koff;
    const float* wrow[5];
    if (role == 0) {
        wrow[0] = Whh + rowoff;                 // LSTM i
        wrow[1] = Whh + rstep + rowoff;         // LSTM f
        wrow[2] = Whh + 2 * rstep + rowoff;     // LSTM g
        wrow[3] = Whh + 3 * rstep + rowoff;     // LSTM o
        wrow[4] = gWhh + rowoff;                // GRU gh_r
    } else {
        wrow[0] = gWhh + rstep + rowoff;        // GRU gh_z
        wrow[1] = gWhh + 2 * rstep + rowoff;    // GRU gh_n
        wrow[2] = gWih + rowoff;                // GRU gi_r
        wrow[3] = gWih + rstep + rowoff;        // GRU gi_z
        wrow[4] = gWih + 2 * rstep + rowoff;    // GRU gi_n
    }
    s16x8 w5[5][8];
#pragma unroll
    for (int q = 0; q < 5; ++q)
#pragma unroll
        for (int it = 0; it < 8; ++it)
            w5[q][it] = cvt8(wrow[q] + it * 32);

    // ---- per-element master state + biases (all 512 threads: 32b x 16cell) ----
    const int cell = tid & 15;
    const int bq = tid >> 4;                 // 0..31
    const int gidx = bq * HH + kk0 + cell;
    float st_m;                              // role0: c master, role1: hg master
    float b0 = 0.f, b1 = 0.f, b2 = 0.f, b3 = 0.f;
    {
        st_m = feat[gidx];
        if (role == 0) {
            b0 = gbhh[kk0 + cell];                    // bhh_r (goes with gh_r)
        } else {
            b0 = gbih[kk0 + cell];                    // bih_r
            b1 = gbih[HH + kk0 + cell] + gbhh[HH + kk0 + cell];      // z biases
            b2 = gbih[2 * HH + kk0 + cell];           // bih_n
            b3 = gbhh[2 * HH + kk0 + cell];           // bhh_n (inside r*)
        }
    }

    unsigned int nbar = 0;
    for (int t = 0; t < TS; ++t) {
        const unsigned short* hin  = (t & 1) ? hbf1 : hbf0;
        unsigned short*       hout = (t & 1) ? hbf0 : hbf1;

        // ---------------- P1 MFMAs ----------------
        {
            f32x4 acc[5][2];
#pragma unroll
            for (int q = 0; q < 5; ++q) {
                acc[q][0] = (f32x4){0.f, 0.f, 0.f, 0.f};
                acc[q][1] = (f32x4){0.f, 0.f, 0.f, 0.f};
            }
            if (role == 0) {
                const unsigned short* Ah = hin  + (size_t)l15 * HH + koff;
                const unsigned short* Ag = hgbf + (size_t)l15 * HH + koff;
#pragma unroll
                for (int it = 0; it < 8; ++it) {
                    s16x8 ah0 = cohload16(Ah + it * 32);
                    s16x8 ah1 = cohload16(Ah + 16 * HH + it * 32);
                    s16x8 ag0 = cohload16(Ag + it * 32);
                    s16x8 ag1 = cohload16(Ag + 16 * HH + it * 32);
                    acc[0][0] = __builtin_amdgcn_mfma_f32_16x16x32_bf16(ah0, w5[0][it], acc[0][0], 0, 0, 0);
                    acc[0][1] = __builtin_amdgcn_mfma_f32_16x16x32_bf16(ah1, w5[0][it], acc[0][1], 0, 0, 0);
                    acc[1][0] = __builtin_amdgcn_mfma_f32_16x16x32_bf16(ah0, w5[1][it], acc[1][0], 0, 0, 0);
                    acc[1][1] = __builtin_amdgcn_mfma_f32_16x16x32_bf16(ah1, w5[1][it], acc[1][1], 0, 0, 0);
                    acc[2][0] = __builtin_amdgcn_mfma_f32_16x16x32_bf16(ah0, w5[2][it], acc[2][0], 0, 0, 0);
                    acc[2][1] = __builtin_amdgcn_mfma_f32_16x16x32_bf16(ah1, w5[2][it], acc[2][1], 0, 0, 0);
                    acc[3][0] = __builtin_amdgcn_mfma_f32_16x16x32_bf16(ah0, w5[3][it], acc[3][0], 0, 0, 0);
                    acc[3][1] = __builtin_amdgcn_mfma_f32_16x16x32_bf16(ah1, w5[3][it], acc[3][1], 0, 0, 0);
                    acc[4][0] = __builtin_amdgcn_mfma_f32_16x16x32_bf16(ag0, w5[4][it], acc[4][0], 0, 0, 0);
                    acc[4][1] = __builtin_amdgcn_mfma_f32_16x16x32_bf16(ag1, w5[4][it], acc[4][1], 0, 0, 0);
                }
#pragma unroll
                for (int q = 0; q < 5; ++q)
#pragma unroll
                    for (int r = 0; r < 4; ++r) {
                        lsum[q][w][lq * 4 + r][l15]      = acc[q][0][r];
                        lsum[q][w][16 + lq * 4 + r][l15] = acc[q][1][r];
                    }
            } else {
                const unsigned short* Ag = hgbf + (size_t)l15 * HH + koff;
#pragma unroll
                for (int it = 0; it < 8; ++it) {
                    s16x8 ag0 = cohload16(Ag + it * 32);
                    s16x8 ag1 = cohload16(Ag + 16 * HH + it * 32);
                    acc[0][0] = __builtin_amdgcn_mfma_f32_16x16x32_bf16(ag0, w5[0][it], acc[0][0], 0, 0, 0);
                    acc[0][1] = __builtin_amdgcn_mfma_f32_16x16x32_bf16(ag1, w5[0][it], acc[0][1], 0, 0, 0);
                    acc[1][0] = __builtin_amdgcn_mfma_f32_16x16x32_bf16(ag0, w5[1][it], acc[1][0], 0, 0, 0);
                    acc[1][1] = __builtin_amdgcn_mfma_f32_16x16x32_bf16(ag1, w5[1][it], acc[1][1], 0, 0, 0);
                }
#pragma unroll
                for (int q = 0; q < 2; ++q)
#pragma unroll
                    for (int r = 0; r < 4; ++r) {
                        lsum[q][w][lq * 4 + r][l15]      = acc[q][0][r];
                        lsum[q][w][16 + lq * 4 + r][l15] = acc[q][1][r];
                    }
            }
        }
        __syncthreads();

        // ---------------- P1 epilogue (role 0): LSTM c,h + export gh_r ------
        if (role == 0) {
            float s0 = 0.f, s1 = 0.f, s2 = 0.f, s3 = 0.f, s4 = 0.f;
#pragma unroll
            for (int wv = 0; wv < 8; ++wv) {
                s0 += lsum[0][wv][bq][cell];
                s1 += lsum[1][wv][bq][cell];
                s2 += lsum[2][wv][bq][cell];
                s3 += lsum[3][wv][bq][cell];
                s4 += lsum[4][wv][bq][cell];
            }
            const float* xwb = xw + ((size_t)t * BB + bq) * 4 * HH + kk0 + cell;
            float c = sigmf(s1 + xwb[HH]) * st_m + sigmf(s0 + xwb[0]) * tanhf_fast(s2 + xwb[2 * HH]);
            float h = sigmf(s3 + xwb[3 * HH]) * tanhf_fast(c);
            st_m = c;
            // paired u32 coherent stores (cell pairs are wave-contiguous)
            unsigned cu = f2bf(c), hu = f2bf(h);
            unsigned cup = __shfl_down(cu, 1);
            unsigned hup = __shfl_down(hu, 1);
            if ((cell & 1) == 0) {
                __hip_atomic_store((unsigned*)(cbf + gidx),  cu | (cup << 16),
                                   __ATOMIC_RELAXED, __HIP_MEMORY_SCOPE_AGENT);
                __hip_atomic_store((unsigned*)(hout + gidx), hu | (hup << 16),
                                   __ATOMIC_RELAXED, __HIP_MEMORY_SCOPE_AGENT);
            }
            __hip_atomic_store((unsigned*)&gh0_g[strip * 512 + tid],
                               __float_as_uint(s4 + b0),
                               __ATOMIC_RELAXED, __HIP_MEMORY_SCOPE_AGENT);
        }
        grid_sync(flags, go, ++nbar);      // c, h, gh_r visible everywhere

        // ---------------- P2 (role 1): gi MFMAs + GRU epilogue ----------------
        if (role == 1) {
            {
                const unsigned short* Ac = cbf + (size_t)l15 * HH + koff;
                f32x4 acc[3][2];
#pragma unroll
                for (int q = 0; q < 3; ++q) {
                    acc[q][0] = (f32x4){0.f, 0.f, 0.f, 0.f};
                    acc[q][1] = (f32x4){0.f, 0.f, 0.f, 0.f};
                }
#pragma unroll
                for (int it = 0; it < 8; ++it) {
                    s16x8 ac0 = cohload16(Ac + it * 32);
                    s16x8 ac1 = cohload16(Ac + 16 * HH + it * 32);
                    acc[0][0] = __builtin_amdgcn_mfma_f32_16x16x32_bf16(ac0, w5[2][it], acc[0][0], 0, 0, 0);
                    acc[0][1] = __builtin_amdgcn_mfma_f32_16x16x32_bf16(ac1, w5[2][it], acc[0][1], 0, 0, 0);
                    acc[1][0] = __builtin_amdgcn_mfma_f32_16x16x32_bf16(ac0, w5[3][it], acc[1][0], 0, 0, 0);
                    acc[1][1] = __builtin_amdgcn_mfma_f32_16x16x32_bf16(ac1, w5[3][it], acc[1][1], 0, 0, 0);
                    acc[2][0] = __builtin_amdgcn_mfma_f32_16x16x32_bf16(ac0, w5[4][it], acc[2][0], 0, 0, 0);
                    acc[2][1] = __builtin_amdgcn_mfma_f32_16x16x32_bf16(ac1, w5[4][it], acc[2][1], 0, 0, 0);
                }
#pragma unroll
                for (int q = 0; q < 3; ++q)
#pragma unroll
                    for (int r = 0; r < 4; ++r) {
                        lsum[2 + q][w][lq * 4 + r][l15]      = acc[q][0][r];
                        lsum[2 + q][w][16 + lq * 4 + r][l15] = acc[q][1][r];
                    }
            }
            __syncthreads();
            {
                float gz = 0.f, gn = 0.f, i0 = 0.f, i1 = 0.f, i2 = 0.f;
#pragma unroll
                for (int wv = 0; wv < 8; ++wv) {
                    gz += lsum[0][wv][bq][cell];   // gh_z (from P1, preserved)
                    gn += lsum[1][wv][bq][cell];   // gh_n (from P1, preserved)
                    i0 += lsum[2][wv][bq][cell];   // gi_r
                    i1 += lsum[3][wv][bq][cell];   // gi_z
                    i2 += lsum[4][wv][bq][cell];   // gi_n
                }
                float gr = __uint_as_float(
                    __hip_atomic_load((unsigned*)&gh0_g[strip * 512 + tid],
                                      __ATOMIC_RELAXED, __HIP_MEMORY_SCOPE_AGENT));
                float r = sigmf(i0 + b0 + gr);
                float z = sigmf(i1 + b1 + gz);
                float n = tanhf_fast(i2 + b2 + r * (gn + b3));
                float hg = (1.f - z) * n + z * st_m;
                st_m = hg;
                unsigned short hb = f2bf(hg);
                hg_all[(size_t)t * BB * HH + gidx] = hb;    // normal (read post-kernel)
                unsigned gu = hb;
                unsigned gup = __shfl_down(gu, 1);
                if ((cell & 1) == 0)
                    __hip_atomic_store((unsigned*)(hgbf + gidx), gu | (gup << 16),
                                       __ATOMIC_RELAXED, __HIP_MEMORY_SCOPE_AGENT);
            }
        }
        if (t < TS - 1)
            grid_sync(flags, go, ++nbar);  // h, hg visible for next step
    }
}

// ---------------------------------------------------------------------------
// Phase C: out = hg_all @ linW.T + b. bf16 MFMA, 128x128 tile, BK=32.
// ---------------------------------------------------------------------------
__global__ __launch_bounds__(256) void out_gemm_kernel(
    const unsigned short* __restrict__ A,     // [1280][2048] (rows >=1248 junk)
    const unsigned short* __restrict__ Wl,    // [8000][2048] (reads to 8063 ok)
    const float* __restrict__ bl,
    float* __restrict__ out) {
    __shared__ unsigned short As[128][32];
    __shared__ unsigned short Bs[128][32];
    const int tid = threadIdx.x;
    const int lane = tid & 63;
    const int w = tid >> 6;
    const int l15 = lane & 15;
    const int lq = lane >> 4;
    const int mt = blockIdx.x, nt = blockIdx.y;
    const int mq = w >> 1, nq = w & 1;

    const int row0 = tid >> 2, kc0 = (tid & 3) * 8;
    const unsigned short* Ap0 = A + (size_t)(mt * 128 + row0) * HH + kc0;
    const unsigned short* Ap1 = A + (size_t)(mt * 128 + 64 + row0) * HH + kc0;
    const unsigned short* Bp0 = Wl + (size_t)(nt * 128 + row0) * HH + kc0;
    const unsigned short* Bp1 = Wl + (size_t)(nt * 128 + 64 + row0) * HH + kc0;

    f32x4 acc[4][4];
#pragma unroll
    for (int i = 0; i < 4; ++i)
#pragma unroll
        for (int j = 0; j < 4; ++j) acc[i][j] = (f32x4){0.f, 0.f, 0.f, 0.f};

    for (int k0 = 0; k0 < HH; k0 += 32) {
        s16x8 a0v = *(const s16x8*)(Ap0 + k0);
        s16x8 a1v = *(const s16x8*)(Ap1 + k0);
        s16x8 b0v = *(const s16x8*)(Bp0 + k0);
        s16x8 b1v = *(const s16x8*)(Bp1 + k0);
        *(s16x8*)&As[row0][kc0]      = a0v;
        *(s16x8*)&As[64 + row0][kc0] = a1v;
        *(s16x8*)&Bs[row0][kc0]      = b0v;
        *(s16x8*)&Bs[64 + row0][kc0] = b1v;
        __syncthreads();
        s16x8 af[4], bf[4];
#pragma unroll
        for (int i = 0; i < 4; ++i) af[i] = *(const s16x8*)&As[mq * 64 + i * 16 + l15][lq * 8];
#pragma unroll
        for (int j = 0; j < 4; ++j) bf[j] = *(const s16x8*)&Bs[nq * 64 + j * 16 + l15][lq * 8];
#pragma unroll
        for (int i = 0; i < 4; ++i)
#pragma unroll
            for (int j = 0; j < 4; ++j)
                acc[i][j] = __builtin_amdgcn_mfma_f32_16x16x32_bf16(af[i], bf[j], acc[i][j], 0, 0, 0);
        __syncthreads();
    }
#pragma unroll
    for (int j = 0; j < 4; ++j) {
        int n = nt * 128 + nq * 64 + j * 16 + l15;
        float bn = bl[n < VV ? n : VV - 1];
#pragma unroll
        for (int i = 0; i < 4; ++i) {
#pragma unroll
            for (int r = 0; r < 4; ++r) {
                int m = mt * 128 + mq * 64 + i * 16 + lq * 4 + r;
                if (m < TS * BB && n < VV) {
                    int t = m >> 5, b = m & 31;
                    out[((size_t)b * TS + t) * VV + n] = acc[i][j][r] + bn;
                }
            }
        }
    }
}

// ---------------------------------------------------------------------------
extern "C" void kernel_launch(void* const* d_in, const int* in_sizes, int n_in,
                              void* d_out, int out_size, void* d_ws, size_t ws_size,
                              hipStream_t stream) {
    const float* features = (const float*)d_in[0];
    const int*   captions = (const int*)d_in[1];
    const float* emb      = (const float*)d_in[2];
    const float* lstm_Wih = (const float*)d_in[3];
    const float* lstm_bih = (const float*)d_in[4];
    const float* lstm_Whh = (const float*)d_in[5];
    const float* lstm_bhh = (const float*)d_in[6];
    const float* gru_Wih  = (const float*)d_in[7];
    const float* gru_bih  = (const float*)d_in[8];
    const float* gru_Whh  = (const float*)d_in[9];
    const float* gru_bhh  = (const float*)d_in[10];
    const float* lin_W    = (const float*)d_in[11];
    const float* lin_b    = (const float*)d_in[12];
    float* out = (float*)d_out;

    // workspace layout
    unsigned short* us = (unsigned short*)d_ws;
    unsigned short* linW_bf = us;                              // 8000*2048
    unsigned short* hbf0    = linW_bf + (size_t)VV * HH;       // (out_gemm may
    unsigned short* hbf1    = hbf0 + BB * HH;                  //  over-read into
    unsigned short* cbf     = hbf1 + BB * HH;                  //  these - benign)
    unsigned short* hgbf    = cbf  + BB * HH;
    unsigned short* hg_all  = hgbf + BB * HH;                  // 1280*2048 (padded)
    float* xw = (float*)(hg_all + (size_t)1280 * HH);          // 39*32*8192
    float* gh0_g = xw + (size_t)TS * BB * 4 * HH;              // 128*512
    unsigned int* flags = (unsigned int*)(gh0_g + 128 * 512);  // 256*16 + go
    unsigned int* go = flags + NBLK * 16;

    // 1) bf16 convert for the output GEMM weight only
    convert_kernel<<<(VV * HH / 4 + 255) / 256, 256, 0, stream>>>(lin_W, linW_bf, VV * HH / 4);

    // 2) precompute x-side gate biases for all steps
    embed_proj_kernel<<<dim3(4 * HH / 256, TS), 256, 0, stream>>>(
        captions, emb, lstm_Wih, lstm_bih, lstm_bhh, xw);

    // 3) init bf16 states + zero barrier flags
    init_state_kernel<<<(BB * HH) / 256, 256, 0, stream>>>(features, hbf0, hgbf, flags);

    // 4) persistent recurrence: 5 weight tiles/block register-resident
    recurrence_kernel<<<NBLK, 512, 0, stream>>>(
        lstm_Whh, gru_Whh, gru_Wih, gru_bhh, gru_bih, features, xw,
        hbf0, hbf1, hgbf, cbf, gh0_g, hg_all, flags, go);

    // 5) output projection
    out_gemm_kernel<<<dim3((TS * BB + 127) / 128, (VV + 127) / 128), 256, 0, stream>>>(
        hg_all, linW_bf, lin_b, out);
}